// Round 9
// baseline (148.293 us; speedup 1.0000x reference)
//
#include <hip/hip_runtime.h>
#include <math.h>

#define B_ 4
#define T_ 2048
#define E_ 1024
#define H_ 16
#define D_ 64
#define CHUNK_ 128
#define NC_ 16
#define BH_ (B_ * H_)   // 64
#define M_ (B_ * T_)    // 8192

typedef __attribute__((ext_vector_type(8))) short bf16x8;
typedef __attribute__((ext_vector_type(4))) float f32x4;

__device__ __forceinline__ ushort rnbf(float f) {
  unsigned u = __float_as_uint(f);
  unsigned r = (u + 0x7FFFu + ((u >> 16) & 1u)) >> 16;
  return (ushort)r;
}

__device__ __forceinline__ float bf2f(short s) {
  return __uint_as_float(((unsigned)(ushort)s) << 16);
}

__device__ __forceinline__ void gload_lds16(const void* g, void* l) {
  __builtin_amdgcn_global_load_lds(
      (const __attribute__((address_space(1))) unsigned int*)g,
      (__attribute__((address_space(3))) unsigned int*)l, 16, 0, 0);
}

#define VMW(N) do { asm volatile("s_waitcnt vmcnt(" #N ")" ::: "memory"); \
                    __builtin_amdgcn_sched_barrier(0); } while (0)
#define BARR() do { __builtin_amdgcn_s_barrier(); \
                    __builtin_amdgcn_sched_barrier(0); } while (0)
#define LGK0() do { asm volatile("s_waitcnt lgkmcnt(0)" ::: "memory"); \
                    __builtin_amdgcn_sched_barrier(0); } while (0)

// ---------------------------------------------------------------------------
// fused fp32 -> bf16 conversion for x, w_attn, w_proj (one launch)
// ---------------------------------------------------------------------------
#define N4X_ (M_ * E_ / 4)
#define N4A_ (3 * E_ * E_ / 4)
__global__ __launch_bounds__(256) void k_cvt3(
    const float* __restrict__ x, const float* __restrict__ wa,
    const float* __restrict__ wp, ushort* __restrict__ xb,
    ushort* __restrict__ wab, ushort* __restrict__ wpb) {
  int i = blockIdx.x * 256 + threadIdx.x;
  const float* src;
  ushort* dst;
  int off;
  if (i < N4X_) { src = x; dst = xb; off = i; }
  else if (i < N4X_ + N4A_) { src = wa; dst = wab; off = i - N4X_; }
  else { src = wp; dst = wpb; off = i - (N4X_ + N4A_); }
  float4 v = ((const float4*)src)[off];
  ushort4 o;
  o.x = rnbf(v.x); o.y = rnbf(v.y); o.z = rnbf(v.z); o.w = rnbf(v.w);
  ((ushort4*)dst)[off] = o;
}

// ---------------------------------------------------------------------------
// Kernel 1 (k_qkv3): qkv = x @ w_attn^T, 256x256 tile, BK=64, per-wave
// 128x64 (0.375 ds_read/MFMA), 128 KB LDS 2-buf, 1 block/CU, grid 384.
// LDS per buf: A[2 kh-planes][256][32] + B[same] (row stride 64B, chunk-XOR
// swizzle as in the proven 48KB kernel; pre-swizzled gload sources).
// Ledger: prologue stages tiles 0,1 (8 loads/thread each); iter t:
// VMW(8) [waits tile t, leaves tile t+1 in flight] -> BARR -> 64 MFMA ->
// BARR -> stage tile t+2. Peeled t=14 (VMW(8)) and t=15 (VMW(0)).
// NOTE: launch_bounds min-waves MUST stay <=2: (512,6) caps VGPR at 85 and
// spills acc (R7: 456us, 2GB scratch).
// ---------------------------------------------------------------------------
#define STG3(buf_, tt_) { \
  gload_lds16(Asrc3  + (size_t)(tt_) * 64,          &lds[(buf_) * 32768 + tid * 8]); \
  gload_lds16(Asrc3  + (size_t)(tt_) * 64 + 131072, &lds[(buf_) * 32768 + 4096 + tid * 8]); \
  gload_lds16(Asrc3b + (size_t)(tt_) * 64,          &lds[(buf_) * 32768 + 8192 + tid * 8]); \
  gload_lds16(Asrc3b + (size_t)(tt_) * 64 + 131072, &lds[(buf_) * 32768 + 12288 + tid * 8]); \
  gload_lds16(Bsrc3  + (size_t)(tt_) * 64,          &lds[(buf_) * 32768 + 16384 + tid * 8]); \
  gload_lds16(Bsrc3  + (size_t)(tt_) * 64 + 131072, &lds[(buf_) * 32768 + 20480 + tid * 8]); \
  gload_lds16(Bsrc3b + (size_t)(tt_) * 64,          &lds[(buf_) * 32768 + 24576 + tid * 8]); \
  gload_lds16(Bsrc3b + (size_t)(tt_) * 64 + 131072, &lds[(buf_) * 32768 + 28672 + tid * 8]); }

#define MM3(i, j, A_, B_) \
  acc[i][j] = __builtin_amdgcn_mfma_f32_16x16x32_bf16(A_, B_, acc[i][j], 0, 0, 0)

#define CMP_KH(buf_, kh_) do { \
  const ushort* ap_ = &lds[(buf_) * 32768 + (kh_) * 8192 + aB3]; \
  const ushort* bp_ = &lds[(buf_) * 32768 + 16384 + (kh_) * 8192 + bB3]; \
  bf16x8 B0 = *(const bf16x8*)bp_;          bf16x8 B1 = *(const bf16x8*)(bp_ + 512); \
  bf16x8 B2 = *(const bf16x8*)(bp_ + 1024); bf16x8 B3 = *(const bf16x8*)(bp_ + 1536); \
  bf16x8 A0 = *(const bf16x8*)ap_;          bf16x8 A1 = *(const bf16x8*)(ap_ + 512); \
  bf16x8 A2 = *(const bf16x8*)(ap_ + 1024); bf16x8 A3 = *(const bf16x8*)(ap_ + 1536); \
  __builtin_amdgcn_s_setprio(1); \
  MM3(0,0,A0,B0); MM3(0,1,A0,B1); MM3(0,2,A0,B2); MM3(0,3,A0,B3); \
  MM3(1,0,A1,B0); MM3(1,1,A1,B1); MM3(1,2,A1,B2); MM3(1,3,A1,B3); \
  MM3(2,0,A2,B0); MM3(2,1,A2,B1); MM3(2,2,A2,B2); MM3(2,3,A2,B3); \
  MM3(3,0,A3,B0); MM3(3,1,A3,B1); MM3(3,2,A3,B2); MM3(3,3,A3,B3); \
  __builtin_amdgcn_s_setprio(0); \
  bf16x8 A4 = *(const bf16x8*)(ap_ + 2048); bf16x8 A5 = *(const bf16x8*)(ap_ + 2560); \
  bf16x8 A6 = *(const bf16x8*)(ap_ + 3072); bf16x8 A7 = *(const bf16x8*)(ap_ + 3584); \
  __builtin_amdgcn_s_setprio(1); \
  MM3(4,0,A4,B0); MM3(4,1,A4,B1); MM3(4,2,A4,B2); MM3(4,3,A4,B3); \
  MM3(5,0,A5,B0); MM3(5,1,A5,B1); MM3(5,2,A5,B2); MM3(5,3,A5,B3); \
  MM3(6,0,A6,B0); MM3(6,1,A6,B1); MM3(6,2,A6,B2); MM3(6,3,A6,B3); \
  MM3(7,0,A7,B0); MM3(7,1,A7,B1); MM3(7,2,A7,B2); MM3(7,3,A7,B3); \
  __builtin_amdgcn_s_setprio(0); \
} while (0)

#define COMPUTE3(buf_) do { CMP_KH(buf_, 0); CMP_KH(buf_, 1); } while (0)

__global__ __launch_bounds__(512, 2) void k_qkv3(
    const ushort* __restrict__ xb, const ushort* __restrict__ wab,
    ushort* __restrict__ qg, ushort* __restrict__ kg,
    ushort* __restrict__ ktg, ushort* __restrict__ vtg,
    float* __restrict__ zp) {
  extern __shared__ ushort lds[];
  const int b = blockIdx.x;
  const int xcd = b & 7, idx = b >> 3;     // idx in [0,48)
  const int bm = xcd * 4 + (idx & 3);      // [0,32)
  const int bn = idx >> 2;                 // [0,12)
  const int tid = threadIdx.x;
  const int wv = tid >> 6, l = tid & 63;
  const int wm = wv >> 2, wn = wv & 3;
  const int c16 = l & 15, g4 = l >> 4;

  const ushort* Ag = xb + (size_t)bm * 256 * 1024;
  const ushort* Bg = wab + (size_t)bn * 256 * 1024;
  // staging sources (pre-swizzled cols; LDS dest linear, G21)
  const int cswz = ((tid & 3) ^ ((tid >> 3) & 3)) * 8;
  const ushort* Asrc3 = Ag + (size_t)(tid >> 2) * 1024 + cswz;        // plane 0
  const ushort* Asrc3b = Asrc3 + 32;                                  // plane 1
  const ushort* Bsrc3 = Bg + (size_t)(tid >> 2) * 1024 + cswz;
  const ushort* Bsrc3b = Bsrc3 + 32;
  // fragment read bases (swizzled, row stride 32 ushorts = 64B)
  const int xcol = (g4 ^ ((c16 >> 1) & 3)) * 8;
  const int aB3 = (wm * 128 + c16) * 32 + xcol;
  const int bB3 = (wn * 64 + c16) * 32 + xcol;

  f32x4 acc[8][4] = {};

  STG3(0, 0);
  STG3(1, 1);
#pragma unroll 2
  for (int t = 0; t < 14; ++t) {
    VMW(8); BARR();
    COMPUTE3(t & 1);
    BARR();
    STG3(t & 1, t + 2);
  }
  { VMW(8); BARR(); COMPUTE3(0); }   // t=14
  { VMW(0); BARR(); COMPUTE3(1); }   // t=15

  // ---- epilogue ---- (after the t=15 barrier, buf0 region is dead for all
  // waves; per-wave scratch lives in [0,16384) = buf0 A planes)
  const int colbase = bn * 256 + wn * 64;
  const int which = colbase >> 10;         // wave-uniform (1024 | 4*256)
  const int h = (colbase & 1023) >> 6;
  const int rowbase = bm * 256 + wm * 128; // one full (bh, chunk) per wave
  const int bidx = rowbase >> 11;
  const int tbase = rowbase & 2047;
  const int cc = tbase >> 7;
  const size_t bh = (size_t)(bidx * 16 + h);
  ushort* wlds2 = &lds[wv * 2048];         // per-wave 32t x 64d buffer (4KB)
  ushort* tg = (which == 1) ? ktg : vtg;
  float zpart[4] = {0.f, 0.f, 0.f, 0.f};
#pragma unroll
  for (int p = 0; p < 4; ++p) {
#pragma unroll
    for (int mh = 0; mh < 2; ++mh) {
      const int mf = p * 2 + mh;
#pragma unroll
      for (int nf = 0; nf < 4; ++nf) {
        float o[4];
#pragma unroll
        for (int j = 0; j < 4; ++j) {
          float u = acc[mf][nf][j];
          o[j] = (which < 2) ? ((u > 0.f) ? u + 1.f : expf(u)) : u;  // elu+1
        }
        const int d = nf * 16 + c16;
        if (which == 1) zpart[nf] += o[0] + o[1] + o[2] + o[3];
        if (which <= 1) {
          ushort* dst = (which == 0) ? qg : kg;
          const size_t rb = (bh * 2048 + tbase + mf * 16 + g4 * 4) * 64 + d;
#pragma unroll
          for (int j = 0; j < 4; ++j) dst[rb + (size_t)j * 64] = rnbf(o[j]);
        }
        if (which >= 1) {
          const int tb2 = (mh * 4 + g4) ^ (d & 7);
          ushort4 pk;
          pk.x = rnbf(o[0]); pk.y = rnbf(o[1]); pk.z = rnbf(o[2]); pk.w = rnbf(o[3]);
          *(ushort4*)&wlds2[d * 32 + tb2 * 4] = pk;
        }
      }
    }
    if (which >= 1) {
      LGK0();  // wave-local ds_writes visible to this wave's reads
#pragma unroll
      for (int rt = 0; rt < 4; ++rt) {
        const int d = rt * 16 + (l >> 2);
        const int t0 = (l & 3) * 8;
        const int ba = ((l & 3) * 2) ^ (d & 7);
        const int bb = ((l & 3) * 2 + 1) ^ (d & 7);
        ushort4 ua = *(const ushort4*)&wlds2[d * 32 + ba * 4];
        ushort4 ub = *(const ushort4*)&wlds2[d * 32 + bb * 4];
        __align__(16) ushort tmp[8] = {ua.x, ua.y, ua.z, ua.w,
                                       ub.x, ub.y, ub.z, ub.w};
        *(bf16x8*)&tg[(bh * 64 + d) * 2048 + tbase + p * 32 + t0] =
            *(const bf16x8*)tmp;
      }
      LGK0();  // reads done before next sub-pass overwrites the buffer
    }
  }
  if (which == 1) {
#pragma unroll
    for (int nf = 0; nf < 4; ++nf) {
      float zz = zpart[nf];
      zz += __shfl_xor(zz, 16);
      zz += __shfl_xor(zz, 32);
      if (l < 16) zp[((bh * NC_ + cc)) * 64 + nf * 16 + l] = zz;
    }
  }
}

// ---------------------------------------------------------------------------
// k_proj2: 128x256 tile, BK=32 2-slab (48KB) core — unchanged, proven.
// ---------------------------------------------------------------------------
#define ABASE(sl_) ((sl_) * 4096)
#define BBASE(sl_) (8192 + (sl_) * 8192)

#define STG(sl_, tt_) { \
  gload_lds16(Asrc + (tt_) * 32, &lds[ABASE(sl_) + tid * 8]); \
  gload_lds16(Bsrc0 + (tt_) * 32, &lds[BBASE(sl_) + tid * 8]); \
  gload_lds16(Bsrc1 + (tt_) * 32, &lds[BBASE(sl_) + tid * 8 + 4096]); }

#define LDFRAGS(sl_) \
  const ushort* pa = &lds[ABASE(sl_) + aOff]; \
  a0 = *(const bf16x8*)pa;          a1 = *(const bf16x8*)(pa + 512); \
  a2 = *(const bf16x8*)(pa + 1024); a3 = *(const bf16x8*)(pa + 1536); \
  const ushort* pb = &lds[BBASE(sl_) + bOff]; \
  b0 = *(const bf16x8*)pb;          b1 = *(const bf16x8*)(pb + 512); \
  b2 = *(const bf16x8*)(pb + 1024); b3 = *(const bf16x8*)(pb + 1536);

#define MM(i, j, A_, B_) \
  acc[i][j] = __builtin_amdgcn_mfma_f32_16x16x32_bf16(A_, B_, acc[i][j], 0, 0, 0)
#define MFMA16() do { __builtin_amdgcn_s_setprio(1); \
  MM(0,0,a0,b0); MM(0,1,a0,b1); MM(0,2,a0,b2); MM(0,3,a0,b3); \
  MM(1,0,a1,b0); MM(1,1,a1,b1); MM(1,2,a1,b2); MM(1,3,a1,b3); \
  MM(2,0,a2,b0); MM(2,1,a2,b1); MM(2,2,a2,b2); MM(2,3,a2,b3); \
  MM(3,0,a3,b0); MM(3,1,a3,b1); MM(3,2,a3,b2); MM(3,3,a3,b3); \
  __builtin_amdgcn_s_setprio(0); } while (0)

__device__ __forceinline__ void pipe_gemm(const ushort* __restrict__ Ag,
                                          const ushort* __restrict__ Bg,
                                          ushort* lds, f32x4 acc[4][4]) {
  const int tid = threadIdx.x;
  const int l = tid & 63, wv = tid >> 6;
  const int wm = wv >> 2, wn = wv & 3;
  const int c16 = l & 15, g4 = l >> 4;
  const int gch = (tid & 3) ^ ((tid >> 3) & 3);
  const ushort* Asrc = Ag + (size_t)(tid >> 2) * 1024 + gch * 8;
  const ushort* Bsrc0 = Bg + (size_t)(tid >> 2) * 1024 + gch * 8;
  const ushort* Bsrc1 = Bsrc0 + (size_t)128 * 1024;
  const int xq = (c16 >> 1) & 3;
  const int aOff = (wm * 64 + c16) * 32 + ((g4 ^ xq) << 3);
  const int bOff = (wn * 64 + c16) * 32 + ((g4 ^ xq) << 3);

  STG(0, 0);
  STG(1, 1);
#pragma unroll 2
  for (int t = 0; t < 30; ++t) {
    const int sl = t & 1;
    VMW(3); BARR();
    bf16x8 a0, a1, a2, a3, b0, b1, b2, b3;
    LDFRAGS(sl);
    MFMA16();
    BARR();
    STG(sl, t + 2);
  }
  {
    VMW(3); BARR();
    bf16x8 a0, a1, a2, a3, b0, b1, b2, b3;
    LDFRAGS(0);
    MFMA16();
  }
  {
    VMW(0); BARR();
    bf16x8 a0, a1, a2, a3, b0, b1, b2, b3;
    LDFRAGS(1);
    MFMA16();
  }
}

__global__ __launch_bounds__(512, 4) void k_proj2(
    const ushort* __restrict__ yb, const ushort* __restrict__ wpb,
    float* __restrict__ out) {
  extern __shared__ ushort lds[];
  const int b = blockIdx.x;
  const int xcd = b & 7, idx = b >> 3;
  const int bm = xcd * 8 + (idx & 7);
  const int bn = idx >> 3;
  const int tid = threadIdx.x;
  const int wv = tid >> 6, l = tid & 63;
  const int wm = wv >> 2, wn = wv & 3;
  const int c16 = l & 15, g4 = l >> 4;

  f32x4 acc[4][4] = {};
  pipe_gemm(yb + (size_t)bm * 128 * 1024, wpb + (size_t)bn * 256 * 1024, lds, acc);

  const int rowbase = bm * 128 + wm * 64 + g4 * 4;
  const int colbase = bn * 256 + wn * 64 + c16;
#pragma unroll
  for (int mf = 0; mf < 4; ++mf)
#pragma unroll
    for (int nf = 0; nf < 4; ++nf) {
      const size_t base = (size_t)(rowbase + mf * 16) * 1024 + colbase + nf * 16;
#pragma unroll
      for (int j = 0; j < 4; ++j)
        out[base + (size_t)j * 1024] = acc[mf][nf][j];
    }
}

// ---------------------------------------------------------------------------
// Kernel 2 (MFMA): per-chunk  ST[e][d] = sum_t v[t][e] k[t][d]  (fp32 out)
// ---------------------------------------------------------------------------
__global__ __launch_bounds__(256) void k_stats(const ushort* __restrict__ ktg,
                                               const ushort* __restrict__ vtg,
                                               float* __restrict__ Sc) {
  __shared__ __align__(16) ushort kT_s[64 * 128], vT_s[64 * 128];
  const int blk = blockIdx.x;
  const int bh = blk >> 4, c = blk & 15;
  const int tid = threadIdx.x;
  const int w = tid >> 6, l = tid & 63;
  const ushort* ktb = ktg + (size_t)bh * D_ * T_ + c * CHUNK_;
  const ushort* vtb = vtg + (size_t)bh * D_ * T_ + c * CHUNK_;
#pragma unroll
  for (int s2 = 0; s2 < 4; ++s2) {
    const int seg = w * 4 + s2;
    const int row = seg * 4 + (l >> 4);
    const int sb = ((l & 15) ^ (row & 7)) * 8;
    gload_lds16(ktb + (size_t)row * T_ + sb, &kT_s[seg * 512]);
    gload_lds16(vtb + (size_t)row * T_ + sb, &vT_s[seg * 512]);
  }
  __syncthreads();
  const int wr = w >> 1, wc = w & 1;
  f32x4 acc[2][2] = {};
#pragma unroll
  for (int kt = 0; kt < 4; ++kt) {
    const int g = kt * 32 + (l >> 4) * 8;
    bf16x8 av[2], bk[2];
#pragma unroll
    for (int rt = 0; rt < 2; ++rt) {
      const int e = wr * 32 + rt * 16 + (l & 15);
      av[rt] = *(const bf16x8*)&vT_s[e * 128 + (g ^ ((e & 7) << 3))];
    }
#pragma unroll
    for (int ct = 0; ct < 2; ++ct) {
      const int d = wc * 32 + ct * 16 + (l & 15);
      bk[ct] = *(const bf16x8*)&kT_s[d * 128 + (g ^ ((d & 7) << 3))];
    }
#pragma unroll
    for (int rt = 0; rt < 2; ++rt)
#pragma unroll
      for (int ct = 0; ct < 2; ++ct)
        acc[rt][ct] = __builtin_amdgcn_mfma_f32_16x16x32_bf16(av[rt], bk[ct],
                                                              acc[rt][ct], 0, 0, 0);
  }
  float* So = Sc + (size_t)blk * 4096;
#pragma unroll
  for (int rt = 0; rt < 2; ++rt)
#pragma unroll
    for (int ct = 0; ct < 2; ++ct)
#pragma unroll
      for (int jj = 0; jj < 4; ++jj)
        So[(wr * 32 + rt * 16 + (l >> 4) * 4 + jj) * 64 + wc * 32 + ct * 16 + (l & 15)] =
            acc[rt][ct][jj];
}

// ---------------------------------------------------------------------------
// Kernel 3: exclusive prefix over 16 chunks, parallelized.
// blocks 0..255: (bh, quarter) S-scan; blocks 256..319: z-scan per bh.
// ---------------------------------------------------------------------------
__global__ __launch_bounds__(256) void k_prefix2(const float* __restrict__ Sc,
                                                 ushort* __restrict__ STb,
                                                 const float* __restrict__ zp,
                                                 float* __restrict__ zout) {
  const int b = blockIdx.x;
  const int tid = threadIdx.x;
  if (b < 256) {
    const int bh = b >> 2, qt = b & 3;
    const float4* Sb = (const float4*)(Sc + (size_t)bh * NC_ * 4096) + qt * 256 + tid;
    ushort4* Ob = (ushort4*)(STb + (size_t)bh * NC_ * 4096) + qt * 256 + tid;
    float4 v[16];
#pragma unroll
    for (int c = 0; c < NC_; ++c) v[c] = Sb[c * 1024];
    float4 acc = make_float4(0.f, 0.f, 0.f, 0.f);
#pragma unroll
    for (int c = 0; c < NC_; ++c) {
      ushort4 o;
      o.x = rnbf(acc.x); o.y = rnbf(acc.y); o.z = rnbf(acc.z); o.w = rnbf(acc.w);
      Ob[c * 1024] = o;
      acc.x += v[c].x; acc.y += v[c].y; acc.z += v[c].z; acc.w += v[c].w;
    }
  } else {
    const int bh = b - 256;
    if (tid < 16) {
      const float4* zpb = (const float4*)(zp + (size_t)bh * NC_ * 64);
      float4* zob = (float4*)(zout + (size_t)bh * NC_ * 64);
      float4 t0[16];
#pragma unroll
      for (int c = 0; c < NC_; ++c) t0[c] = zpb[c * 16 + tid];
      float4 za = make_float4(0.f, 0.f, 0.f, 0.f);
#pragma unroll
      for (int c = 0; c < NC_; ++c) {
        zob[c * 16 + tid] = za;
        za.x += t0[c].x; za.y += t0[c].y;
        za.z += t0[c].z; za.w += t0[c].w;
      }
    }
  }
}

// ---------------------------------------------------------------------------
// Kernel 4 (MFMA): per-chunk output -> y bf16 [B,T,H,D]
// ---------------------------------------------------------------------------
__global__ __launch_bounds__(512, 4) void k_out(
    const ushort* __restrict__ qg, const ushort* __restrict__ kg,
    const ushort* __restrict__ vtg, const ushort* __restrict__ STb,
    const float* __restrict__ zg, ushort* __restrict__ yb) {
  __shared__ __align__(16) ushort k_s[128 * 64];
  __shared__ __align__(16) ushort vT_s[64 * 128];
  __shared__ __align__(16) ushort ST_s[64 * 64];
  __shared__ __align__(16) ushort P_s[128 * 128];
  __shared__ float z_s[64];
  __shared__ float dinter_s[128];
  const int blk = blockIdx.x;
  const int bh = blk >> 4, c = blk & 15;
  const int tid = threadIdx.x;
  const int w = tid >> 6, l = tid & 63;

  const ushort* kbase = kg + ((size_t)bh * T_ + c * CHUNK_) * D_;
  const ushort* vbase = vtg + (size_t)bh * D_ * T_ + c * CHUNK_;
  const ushort* sbase = STb + ((size_t)bh * NC_ + c) * 4096;
  {
    int seg = w, row = seg * 8 + (l >> 3);
    gload_lds16(kbase + (size_t)row * 64 + ((l & 7) ^ (row & 7)) * 8, &k_s[seg * 512]);
    seg = w + 8; row = seg * 8 + (l >> 3);
    gload_lds16(kbase + (size_t)row * 64 + ((l & 7) ^ (row & 7)) * 8, &k_s[seg * 512]);
  }
  {
    int seg = w, row = seg * 4 + (l >> 4);
    gload_lds16(vbase + (size_t)row * T_ + ((l & 15) ^ (row & 7)) * 8, &vT_s[seg * 512]);
    seg = w + 8; row = seg * 4 + (l >> 4);
    gload_lds16(vbase + (size_t)row * T_ + ((l & 15) ^ (row & 7)) * 8, &vT_s[seg * 512]);
  }
  {
    const int seg = w, row = seg * 8 + (l >> 3);
    gload_lds16(sbase + (size_t)row * 64 + ((l & 7) ^ (row & 7)) * 8, &ST_s[seg * 512]);
  }
  if (tid < 64) z_s[tid] = zg[((size_t)bh * NC_ + c) * 64 + tid];
  const int arow = w * 16 + (l & 15);
  const ushort* qrow = qg + ((size_t)bh * T_ + c * CHUNK_ + arow) * D_ + (l >> 4) * 8;
  bf16x8 qf0 = *(const bf16x8*)(qrow);
  bf16x8 qf1 = *(const bf16x8*)(qrow + 32);
  __syncthreads();

  f32x4 sc[8] = {};
#pragma unroll
  for (int jt = 0; jt < 8; ++jt) {
    const int j = jt * 16 + (l & 15);
    const int sw = (j & 7) << 3, g = (l >> 4) * 8;
    bf16x8 b0 = *(const bf16x8*)&k_s[j * 64 + (g ^ sw)];
    bf16x8 b1 = *(const bf16x8*)&k_s[j * 64 + ((g + 32) ^ sw)];
    sc[jt] = __builtin_amdgcn_mfma_f32_16x16x32_bf16(qf0, b0, sc[jt], 0, 0, 0);
    sc[jt] = __builtin_amdgcn_mfma_f32_16x16x32_bf16(qf1, b1, sc[jt], 0, 0, 0);
  }
  const int crow0 = w * 16 + (l >> 4) * 4;
  float rsum[4] = {0.f, 0.f, 0.f, 0.f};
#pragma unroll
  for (int jt = 0; jt < 8; ++jt) {
    const int j = jt * 16 + (l & 15);
#pragma unroll
    for (int jj = 0; jj < 4; ++jj) {
      const int i = crow0 + jj;
      float s = (j <= i) ? sc[jt][jj] : 0.f;
      rsum[jj] += s;
      P_s[i * 128 + (j ^ ((i & 7) << 3))] = rnbf(s);
    }
  }
  float di = 0.f;
#pragma unroll
  for (int jj = 0; jj < 8; ++jj) {
    di = fmaf(bf2f(qf0[jj]), z_s[(l >> 4) * 8 + jj], di);
    di = fmaf(bf2f(qf1[jj]), z_s[32 + (l >> 4) * 8 + jj], di);
  }
  di += __shfl_xor(di, 16);
  di += __shfl_xor(di, 32);
  if (l < 16) dinter_s[w * 16 + l] = di;
#pragma unroll
  for (int jj = 0; jj < 4; ++jj) {
    float r = rsum[jj];
    r += __shfl_xor(r, 1); r += __shfl_xor(r, 2);
    r += __shfl_xor(r, 4); r += __shfl_xor(r, 8);
    rsum[jj] = r;
  }
  __syncthreads();

  f32x4 acc2[4] = {};
#pragma unroll
  for (int et = 0; et < 4; ++et) {
    const int e = et * 16 + (l & 15);
    const int sw = (e & 7) << 3, g = (l >> 4) * 8;
    bf16x8 s0 = *(const bf16x8*)&ST_s[e * 64 + (g ^ sw)];
    bf16x8 s1 = *(const bf16x8*)&ST_s[e * 64 + ((g + 32) ^ sw)];
    acc2[et] = __builtin_amdgcn_mfma_f32_16x16x32_bf16(qf0, s0, acc2[et], 0, 0, 0);
    acc2[et] = __builtin_amdgcn_mfma_f32_16x16x32_bf16(qf1, s1, acc2[et], 0, 0, 0);
  }
  const int prow = w * 16 + (l & 15);
  const int psw = (prow & 7) << 3;
#pragma unroll
  for (int jkt = 0; jkt < 4; ++jkt) {
    bf16x8 pa = *(const bf16x8*)&P_s[prow * 128 + ((jkt * 32 + (l >> 4) * 8) ^ psw)];
#pragma unroll
    for (int et = 0; et < 4; ++et) {
      const int e = et * 16 + (l & 15);
      bf16x8 bv = *(const bf16x8*)&vT_s[e * 128 +
                                        ((jkt * 32 + (l >> 4) * 8) ^ ((e & 7) << 3))];
      acc2[et] = __builtin_amdgcn_mfma_f32_16x16x32_bf16(pa, bv, acc2[et], 0, 0, 0);
    }
  }
  float inv[4];
#pragma unroll
  for (int jj = 0; jj < 4; ++jj)
    inv[jj] = 1.0f / (rsum[jj] + dinter_s[crow0 + jj] + 1e-6f);
  const int b = bh >> 4, h = bh & 15;
#pragma unroll
  for (int et = 0; et < 4; ++et) {
    const int d = et * 16 + (l & 15);
#pragma unroll
    for (int jj = 0; jj < 4; ++jj) {
      const int t = c * CHUNK_ + crow0 + jj;
      yb[((size_t)(b * T_ + t) * H_ + h) * D_ + d] = rnbf(acc2[et][jj] * inv[jj]);
    }
  }
}

// ---------------------------------------------------------------------------
extern "C" void kernel_launch(void* const* d_in, const int* in_sizes, int n_in,
                              void* d_out, int out_size, void* d_ws, size_t ws_size,
                              hipStream_t stream) {
  const float* x = (const float*)d_in[0];
  const float* w_attn = (const float*)d_in[1];
  const float* w_proj = (const float*)d_in[2];
  float* out = (float*)d_out;

  ushort* xb = (ushort*)d_ws;                        // [8192,1024]
  ushort* wab = xb + (size_t)M_ * E_;                // [3072,1024]
  ushort* wpb = wab + (size_t)3 * E_ * E_;           // [1024,1024]
  ushort* qb = wpb + (size_t)E_ * E_;                // [bh][t][d]
  ushort* kbm = qb + (size_t)M_ * E_;                // [bh][t][d]
  ushort* kT = kbm + (size_t)M_ * E_;                // [bh][d][t]
  ushort* vT = kT + (size_t)M_ * E_;                 // [bh][d][t]
  ushort* yb = vT + (size_t)M_ * E_;                 // [B,T,H,D]
  ushort* STb = yb + (size_t)M_ * E_;                // [bh][c][e][d] bf16
  float* Schunk = (float*)(STb + (size_t)BH_ * NC_ * 4096);  // fp32
  float* zpart = Schunk + (size_t)BH_ * NC_ * 4096;  // [bh][c][64]
  float* zout = zpart + (size_t)BH_ * NC_ * 64;      // [bh][c][64]

  k_cvt3<<<12288, 256, 0, stream>>>(x, w_attn, w_proj, xb, wab, wpb);

  hipFuncSetAttribute((const void*)k_qkv3,
                      hipFuncAttributeMaxDynamicSharedMemorySize, 131072);
  hipFuncSetAttribute((const void*)k_proj2,
                      hipFuncAttributeMaxDynamicSharedMemorySize, 49152);

  k_qkv3<<<384, 512, 131072, stream>>>(xb, wab, qb, kbm, kT, vT, zpart);
  k_stats<<<1024, 256, 0, stream>>>(kT, vT, Schunk);
  k_prefix2<<<320, 256, 0, stream>>>(Schunk, STb, zpart, zout);
  k_out<<<1024, 512, 0, stream>>>(qb, kbm, vT, STb, zout, yb);
  k_proj2<<<256, 512, 49152, stream>>>(yb, wpb, out);
}

// Round 10
// 140.269 us; speedup vs baseline: 1.0572x; 1.0572x over previous
//
#include <hip/hip_runtime.h>
#include <math.h>

#define B_ 4
#define T_ 2048
#define E_ 1024
#define H_ 16
#define D_ 64
#define CHUNK_ 128
#define NC_ 16
#define BH_ (B_ * H_)   // 64
#define M_ (B_ * T_)    // 8192

typedef __attribute__((ext_vector_type(8))) short bf16x8;
typedef __attribute__((ext_vector_type(4))) float f32x4;

__device__ __forceinline__ ushort rnbf(float f) {
  unsigned u = __float_as_uint(f);
  unsigned r = (u + 0x7FFFu + ((u >> 16) & 1u)) >> 16;
  return (ushort)r;
}

__device__ __forceinline__ float bf2f(short s) {
  return __uint_as_float(((unsigned)(ushort)s) << 16);
}

__device__ __forceinline__ void gload_lds16(const void* g, void* l) {
  __builtin_amdgcn_global_load_lds(
      (const __attribute__((address_space(1))) unsigned int*)g,
      (__attribute__((address_space(3))) unsigned int*)l, 16, 0, 0);
}

#define VMW(N) do { asm volatile("s_waitcnt vmcnt(" #N ")" ::: "memory"); \
                    __builtin_amdgcn_sched_barrier(0); } while (0)
#define BARR() do { __builtin_amdgcn_s_barrier(); \
                    __builtin_amdgcn_sched_barrier(0); } while (0)
#define LGK0() do { asm volatile("s_waitcnt lgkmcnt(0)" ::: "memory"); \
                    __builtin_amdgcn_sched_barrier(0); } while (0)

// ---------------------------------------------------------------------------
// fused fp32 -> bf16 conversion for x, w_attn, w_proj (one launch)
// ---------------------------------------------------------------------------
#define N4X_ (M_ * E_ / 4)
#define N4A_ (3 * E_ * E_ / 4)
__global__ __launch_bounds__(256) void k_cvt3(
    const float* __restrict__ x, const float* __restrict__ wa,
    const float* __restrict__ wp, ushort* __restrict__ xb,
    ushort* __restrict__ wab, ushort* __restrict__ wpb) {
  int i = blockIdx.x * 256 + threadIdx.x;
  const float* src;
  ushort* dst;
  int off;
  if (i < N4X_) { src = x; dst = xb; off = i; }
  else if (i < N4X_ + N4A_) { src = wa; dst = wab; off = i - N4X_; }
  else { src = wp; dst = wpb; off = i - (N4X_ + N4A_); }
  float4 v = ((const float4*)src)[off];
  ushort4 o;
  o.x = rnbf(v.x); o.y = rnbf(v.y); o.z = rnbf(v.z); o.w = rnbf(v.w);
  ((ushort4*)dst)[off] = o;
}

// ---------------------------------------------------------------------------
// Kernel 1 (k_qkv4): qkv = x @ w_attn^T. 256x256 tile, 8 waves (2Mx4N),
// per-wave 128x64 (0.375 ds_read/MFMA). BK=32, THREE 32KB LDS buffers
// (96 KB), m201-style fine interleave: per tile 2 phases, each
// {ds_reads, 2 gload_lds (tile t+2), BARR, lgkmcnt(0), setprio, 16 MFMA,
// setprio, BARR}. VMW(4) at tile entry waits loads issued 2 tiles earlier;
// 3-buf rotation makes interleaved staging race-free (buf (t+2)%3's last
// readers finished before tile-t entry barrier).
// Data layout identical to R9 (refcheck-proven): per buf A[256][32] @0,
// B[256][32] @8192 ushorts, chunk-XOR swizzle, pre-swizzled gload sources.
// NOTE: launch_bounds min-waves MUST stay <=2 (R7: (512,6) spilled acc,
// 456us / 2GB scratch).
// ---------------------------------------------------------------------------
#define QBUF(b_) ((b_) * 16384)

#define STG4A(buf_, tt_) { \
  gload_lds16(Asrc4 + (size_t)(tt_) * 32,          &lds[QBUF(buf_) + tid * 8]); \
  gload_lds16(Asrc4 + (size_t)(tt_) * 32 + 131072, &lds[QBUF(buf_) + 4096 + tid * 8]); }
#define STG4B(buf_, tt_) { \
  gload_lds16(Bsrc4 + (size_t)(tt_) * 32,          &lds[QBUF(buf_) + 8192 + tid * 8]); \
  gload_lds16(Bsrc4 + (size_t)(tt_) * 32 + 131072, &lds[QBUF(buf_) + 12288 + tid * 8]); }

#define MMQ(i, j, A_, B_) \
  acc[i][j] = __builtin_amdgcn_mfma_f32_16x16x32_bf16(A_, B_, acc[i][j], 0, 0, 0)

#define CL16(Aa, Ab, Ac, Ad, i0, i1, i2, i3) do { \
  __builtin_amdgcn_s_setprio(1); \
  MMQ(i0,0,Aa,B0); MMQ(i0,1,Aa,B1); MMQ(i0,2,Aa,B2); MMQ(i0,3,Aa,B3); \
  MMQ(i1,0,Ab,B0); MMQ(i1,1,Ab,B1); MMQ(i1,2,Ab,B2); MMQ(i1,3,Ab,B3); \
  MMQ(i2,0,Ac,B0); MMQ(i2,1,Ac,B1); MMQ(i2,2,Ac,B2); MMQ(i2,3,Ac,B3); \
  MMQ(i3,0,Ad,B0); MMQ(i3,1,Ad,B1); MMQ(i3,2,Ad,B2); MMQ(i3,3,Ad,B3); \
  __builtin_amdgcn_s_setprio(0); } while (0)

__global__ __launch_bounds__(512, 2) void k_qkv4(
    const ushort* __restrict__ xb, const ushort* __restrict__ wab,
    ushort* __restrict__ qg, ushort* __restrict__ kg,
    ushort* __restrict__ ktg, ushort* __restrict__ vtg,
    float* __restrict__ zp) {
  extern __shared__ ushort lds[];
  const int b = blockIdx.x;
  const int xcd = b & 7, idx = b >> 3;     // idx in [0,48)
  const int bm = xcd * 4 + (idx & 3);      // [0,32)
  const int bn = idx >> 2;                 // [0,12)
  const int tid = threadIdx.x;
  const int wv = tid >> 6, l = tid & 63;
  const int wm = wv >> 2, wn = wv & 3;
  const int c16 = l & 15, g4 = l >> 4;

  const ushort* Ag = xb + (size_t)bm * 256 * 1024;
  const ushort* Bg = wab + (size_t)bn * 256 * 1024;
  const int gch = (tid & 3) ^ ((tid >> 3) & 3);
  const ushort* Asrc4 = Ag + (size_t)(tid >> 2) * 1024 + gch * 8;
  const ushort* Bsrc4 = Bg + (size_t)(tid >> 2) * 1024 + gch * 8;
  const int xcol = (g4 ^ ((c16 >> 1) & 3)) << 3;
  const int aB4 = (wm * 128 + c16) * 32 + xcol;
  const int bB4 = (wn * 64 + c16) * 32 + xcol;

  f32x4 acc[8][4] = {};

  STG4A(0, 0); STG4B(0, 0);
  STG4A(1, 1); STG4B(1, 1);
#pragma unroll 3
  for (int t = 0; t < 30; ++t) {
    const int bf = t % 3;
    const int bn2 = (t + 2) % 3;
    VMW(4); BARR();
    const ushort* ap = &lds[QBUF(bf) + aB4];
    const ushort* bp = &lds[QBUF(bf) + 8192 + bB4];
    bf16x8 B0 = *(const bf16x8*)bp;
    bf16x8 B1 = *(const bf16x8*)(bp + 512);
    bf16x8 B2 = *(const bf16x8*)(bp + 1024);
    bf16x8 B3 = *(const bf16x8*)(bp + 1536);
    bf16x8 A0 = *(const bf16x8*)ap;
    bf16x8 A1 = *(const bf16x8*)(ap + 512);
    bf16x8 A2 = *(const bf16x8*)(ap + 1024);
    bf16x8 A3 = *(const bf16x8*)(ap + 1536);
    STG4A(bn2, t + 2);
    BARR(); LGK0();
    CL16(A0, A1, A2, A3, 0, 1, 2, 3);
    BARR();
    bf16x8 A4 = *(const bf16x8*)(ap + 2048);
    bf16x8 A5 = *(const bf16x8*)(ap + 2560);
    bf16x8 A6 = *(const bf16x8*)(ap + 3072);
    bf16x8 A7 = *(const bf16x8*)(ap + 3584);
    STG4B(bn2, t + 2);
    BARR(); LGK0();
    CL16(A4, A5, A6, A7, 4, 5, 6, 7);
  }
  {  // t=30, buf 0 (no staging)
    VMW(4); BARR();
    const ushort* ap = &lds[QBUF(0) + aB4];
    const ushort* bp = &lds[QBUF(0) + 8192 + bB4];
    bf16x8 B0 = *(const bf16x8*)bp;
    bf16x8 B1 = *(const bf16x8*)(bp + 512);
    bf16x8 B2 = *(const bf16x8*)(bp + 1024);
    bf16x8 B3 = *(const bf16x8*)(bp + 1536);
    bf16x8 A0 = *(const bf16x8*)ap;
    bf16x8 A1 = *(const bf16x8*)(ap + 512);
    bf16x8 A2 = *(const bf16x8*)(ap + 1024);
    bf16x8 A3 = *(const bf16x8*)(ap + 1536);
    BARR(); LGK0();
    CL16(A0, A1, A2, A3, 0, 1, 2, 3);
    BARR();
    bf16x8 A4 = *(const bf16x8*)(ap + 2048);
    bf16x8 A5 = *(const bf16x8*)(ap + 2560);
    bf16x8 A6 = *(const bf16x8*)(ap + 3072);
    bf16x8 A7 = *(const bf16x8*)(ap + 3584);
    BARR(); LGK0();
    CL16(A4, A5, A6, A7, 4, 5, 6, 7);
  }
  {  // t=31, buf 1
    VMW(0); BARR();
    const ushort* ap = &lds[QBUF(1) + aB4];
    const ushort* bp = &lds[QBUF(1) + 8192 + bB4];
    bf16x8 B0 = *(const bf16x8*)bp;
    bf16x8 B1 = *(const bf16x8*)(bp + 512);
    bf16x8 B2 = *(const bf16x8*)(bp + 1024);
    bf16x8 B3 = *(const bf16x8*)(bp + 1536);
    bf16x8 A0 = *(const bf16x8*)ap;
    bf16x8 A1 = *(const bf16x8*)(ap + 512);
    bf16x8 A2 = *(const bf16x8*)(ap + 1024);
    bf16x8 A3 = *(const bf16x8*)(ap + 1536);
    LGK0();
    CL16(A0, A1, A2, A3, 0, 1, 2, 3);
    bf16x8 A4 = *(const bf16x8*)(ap + 2048);
    bf16x8 A5 = *(const bf16x8*)(ap + 2560);
    bf16x8 A6 = *(const bf16x8*)(ap + 3072);
    bf16x8 A7 = *(const bf16x8*)(ap + 3584);
    LGK0();
    CL16(A4, A5, A6, A7, 4, 5, 6, 7);
  }

  // ---- epilogue (R9-proven) ----
  BARR();  // all pipeline LDS reads done; buf0 reused as per-wave scratch
  const int colbase = bn * 256 + wn * 64;
  const int which = colbase >> 10;         // wave-uniform
  const int h = (colbase & 1023) >> 6;
  const int rowbase = bm * 256 + wm * 128; // one full (bh, chunk) per wave
  const int bidx = rowbase >> 11;
  const int tbase = rowbase & 2047;
  const int cc = tbase >> 7;
  const size_t bh = (size_t)(bidx * 16 + h);
  ushort* wlds2 = &lds[wv * 2048];         // per-wave 32t x 64d buffer (4KB)
  ushort* tg = (which == 1) ? ktg : vtg;
  float zpart[4] = {0.f, 0.f, 0.f, 0.f};
#pragma unroll
  for (int p = 0; p < 4; ++p) {
#pragma unroll
    for (int mh = 0; mh < 2; ++mh) {
      const int mf = p * 2 + mh;
#pragma unroll
      for (int nf = 0; nf < 4; ++nf) {
        float o[4];
#pragma unroll
        for (int j = 0; j < 4; ++j) {
          float u = acc[mf][nf][j];
          o[j] = (which < 2) ? ((u > 0.f) ? u + 1.f : expf(u)) : u;  // elu+1
        }
        const int d = nf * 16 + c16;
        if (which == 1) zpart[nf] += o[0] + o[1] + o[2] + o[3];
        if (which <= 1) {
          ushort* dst = (which == 0) ? qg : kg;
          const size_t rb = (bh * 2048 + tbase + mf * 16 + g4 * 4) * 64 + d;
#pragma unroll
          for (int j = 0; j < 4; ++j) dst[rb + (size_t)j * 64] = rnbf(o[j]);
        }
        if (which >= 1) {
          const int tb2 = (mh * 4 + g4) ^ (d & 7);
          ushort4 pk;
          pk.x = rnbf(o[0]); pk.y = rnbf(o[1]); pk.z = rnbf(o[2]); pk.w = rnbf(o[3]);
          *(ushort4*)&wlds2[d * 32 + tb2 * 4] = pk;
        }
      }
    }
    if (which >= 1) {
      LGK0();
#pragma unroll
      for (int rt = 0; rt < 4; ++rt) {
        const int d = rt * 16 + (l >> 2);
        const int t0 = (l & 3) * 8;
        const int ba = ((l & 3) * 2) ^ (d & 7);
        const int bb = ((l & 3) * 2 + 1) ^ (d & 7);
        ushort4 ua = *(const ushort4*)&wlds2[d * 32 + ba * 4];
        ushort4 ub = *(const ushort4*)&wlds2[d * 32 + bb * 4];
        __align__(16) ushort tmp[8] = {ua.x, ua.y, ua.z, ua.w,
                                       ub.x, ub.y, ub.z, ub.w};
        *(bf16x8*)&tg[(bh * 64 + d) * 2048 + tbase + p * 32 + t0] =
            *(const bf16x8*)tmp;
      }
      LGK0();
    }
  }
  if (which == 1) {
#pragma unroll
    for (int nf = 0; nf < 4; ++nf) {
      float zz = zpart[nf];
      zz += __shfl_xor(zz, 16);
      zz += __shfl_xor(zz, 32);
      if (l < 16) zp[((bh * NC_ + cc)) * 64 + nf * 16 + l] = zz;
    }
  }
}

// ---------------------------------------------------------------------------
// k_proj2: 128x256 tile, BK=32 2-slab (48KB) core — unchanged, proven.
// ---------------------------------------------------------------------------
#define ABASE(sl_) ((sl_) * 4096)
#define BBASE(sl_) (8192 + (sl_) * 8192)

#define STG(sl_, tt_) { \
  gload_lds16(Asrc + (tt_) * 32, &lds[ABASE(sl_) + tid * 8]); \
  gload_lds16(Bsrc0 + (tt_) * 32, &lds[BBASE(sl_) + tid * 8]); \
  gload_lds16(Bsrc1 + (tt_) * 32, &lds[BBASE(sl_) + tid * 8 + 4096]); }

#define LDFRAGS(sl_) \
  const ushort* pa = &lds[ABASE(sl_) + aOff]; \
  a0 = *(const bf16x8*)pa;          a1 = *(const bf16x8*)(pa + 512); \
  a2 = *(const bf16x8*)(pa + 1024); a3 = *(const bf16x8*)(pa + 1536); \
  const ushort* pb = &lds[BBASE(sl_) + bOff]; \
  b0 = *(const bf16x8*)pb;          b1 = *(const bf16x8*)(pb + 512); \
  b2 = *(const bf16x8*)(pb + 1024); b3 = *(const bf16x8*)(pb + 1536);

#define MM(i, j, A_, B_) \
  acc[i][j] = __builtin_amdgcn_mfma_f32_16x16x32_bf16(A_, B_, acc[i][j], 0, 0, 0)
#define MFMA16() do { __builtin_amdgcn_s_setprio(1); \
  MM(0,0,a0,b0); MM(0,1,a0,b1); MM(0,2,a0,b2); MM(0,3,a0,b3); \
  MM(1,0,a1,b0); MM(1,1,a1,b1); MM(1,2,a1,b2); MM(1,3,a1,b3); \
  MM(2,0,a2,b0); MM(2,1,a2,b1); MM(2,2,a2,b2); MM(2,3,a2,b3); \
  MM(3,0,a3,b0); MM(3,1,a3,b1); MM(3,2,a3,b2); MM(3,3,a3,b3); \
  __builtin_amdgcn_s_setprio(0); } while (0)

__device__ __forceinline__ void pipe_gemm(const ushort* __restrict__ Ag,
                                          const ushort* __restrict__ Bg,
                                          ushort* lds, f32x4 acc[4][4]) {
  const int tid = threadIdx.x;
  const int l = tid & 63, wv = tid >> 6;
  const int wm = wv >> 2, wn = wv & 3;
  const int c16 = l & 15, g4 = l >> 4;
  const int gch = (tid & 3) ^ ((tid >> 3) & 3);
  const ushort* Asrc = Ag + (size_t)(tid >> 2) * 1024 + gch * 8;
  const ushort* Bsrc0 = Bg + (size_t)(tid >> 2) * 1024 + gch * 8;
  const ushort* Bsrc1 = Bsrc0 + (size_t)128 * 1024;
  const int xq = (c16 >> 1) & 3;
  const int aOff = (wm * 64 + c16) * 32 + ((g4 ^ xq) << 3);
  const int bOff = (wn * 64 + c16) * 32 + ((g4 ^ xq) << 3);

  STG(0, 0);
  STG(1, 1);
#pragma unroll 2
  for (int t = 0; t < 30; ++t) {
    const int sl = t & 1;
    VMW(3); BARR();
    bf16x8 a0, a1, a2, a3, b0, b1, b2, b3;
    LDFRAGS(sl);
    MFMA16();
    BARR();
    STG(sl, t + 2);
  }
  {
    VMW(3); BARR();
    bf16x8 a0, a1, a2, a3, b0, b1, b2, b3;
    LDFRAGS(0);
    MFMA16();
  }
  {
    VMW(0); BARR();
    bf16x8 a0, a1, a2, a3, b0, b1, b2, b3;
    LDFRAGS(1);
    MFMA16();
  }
}

__global__ __launch_bounds__(512, 4) void k_proj2(
    const ushort* __restrict__ yb, const ushort* __restrict__ wpb,
    float* __restrict__ out) {
  extern __shared__ ushort lds[];
  const int b = blockIdx.x;
  const int xcd = b & 7, idx = b >> 3;
  const int bm = xcd * 8 + (idx & 7);
  const int bn = idx >> 3;
  const int tid = threadIdx.x;
  const int wv = tid >> 6, l = tid & 63;
  const int wm = wv >> 2, wn = wv & 3;
  const int c16 = l & 15, g4 = l >> 4;

  f32x4 acc[4][4] = {};
  pipe_gemm(yb + (size_t)bm * 128 * 1024, wpb + (size_t)bn * 256 * 1024, lds, acc);

  const int rowbase = bm * 128 + wm * 64 + g4 * 4;
  const int colbase = bn * 256 + wn * 64 + c16;
#pragma unroll
  for (int mf = 0; mf < 4; ++mf)
#pragma unroll
    for (int nf = 0; nf < 4; ++nf) {
      const size_t base = (size_t)(rowbase + mf * 16) * 1024 + colbase + nf * 16;
#pragma unroll
      for (int j = 0; j < 4; ++j)
        out[base + (size_t)j * 1024] = acc[mf][nf][j];
    }
}

// ---------------------------------------------------------------------------
// Kernel 2 (MFMA): per-chunk  ST[e][d] = sum_t v[t][e] k[t][d]  (fp32 out)
// ---------------------------------------------------------------------------
__global__ __launch_bounds__(256) void k_stats(const ushort* __restrict__ ktg,
                                               const ushort* __restrict__ vtg,
                                               float* __restrict__ Sc) {
  __shared__ __align__(16) ushort kT_s[64 * 128], vT_s[64 * 128];
  const int blk = blockIdx.x;
  const int bh = blk >> 4, c = blk & 15;
  const int tid = threadIdx.x;
  const int w = tid >> 6, l = tid & 63;
  const ushort* ktb = ktg + (size_t)bh * D_ * T_ + c * CHUNK_;
  const ushort* vtb = vtg + (size_t)bh * D_ * T_ + c * CHUNK_;
#pragma unroll
  for (int s2 = 0; s2 < 4; ++s2) {
    const int seg = w * 4 + s2;
    const int row = seg * 4 + (l >> 4);
    const int sb = ((l & 15) ^ (row & 7)) * 8;
    gload_lds16(ktb + (size_t)row * T_ + sb, &kT_s[seg * 512]);
    gload_lds16(vtb + (size_t)row * T_ + sb, &vT_s[seg * 512]);
  }
  __syncthreads();
  const int wr = w >> 1, wc = w & 1;
  f32x4 acc[2][2] = {};
#pragma unroll
  for (int kt = 0; kt < 4; ++kt) {
    const int g = kt * 32 + (l >> 4) * 8;
    bf16x8 av[2], bk[2];
#pragma unroll
    for (int rt = 0; rt < 2; ++rt) {
      const int e = wr * 32 + rt * 16 + (l & 15);
      av[rt] = *(const bf16x8*)&vT_s[e * 128 + (g ^ ((e & 7) << 3))];
    }
#pragma unroll
    for (int ct = 0; ct < 2; ++ct) {
      const int d = wc * 32 + ct * 16 + (l & 15);
      bk[ct] = *(const bf16x8*)&kT_s[d * 128 + (g ^ ((d & 7) << 3))];
    }
#pragma unroll
    for (int rt = 0; rt < 2; ++rt)
#pragma unroll
      for (int ct = 0; ct < 2; ++ct)
        acc[rt][ct] = __builtin_amdgcn_mfma_f32_16x16x32_bf16(av[rt], bk[ct],
                                                              acc[rt][ct], 0, 0, 0);
  }
  float* So = Sc + (size_t)blk * 4096;
#pragma unroll
  for (int rt = 0; rt < 2; ++rt)
#pragma unroll
    for (int ct = 0; ct < 2; ++ct)
#pragma unroll
      for (int jj = 0; jj < 4; ++jj)
        So[(wr * 32 + rt * 16 + (l >> 4) * 4 + jj) * 64 + wc * 32 + ct * 16 + (l & 15)] =
            acc[rt][ct][jj];
}

// ---------------------------------------------------------------------------
// Kernel 3: exclusive prefix over 16 chunks, parallelized.
// ---------------------------------------------------------------------------
__global__ __launch_bounds__(256) void k_prefix2(const float* __restrict__ Sc,
                                                 ushort* __restrict__ STb,
                                                 const float* __restrict__ zp,
                                                 float* __restrict__ zout) {
  const int b = blockIdx.x;
  const int tid = threadIdx.x;
  if (b < 256) {
    const int bh = b >> 2, qt = b & 3;
    const float4* Sb = (const float4*)(Sc + (size_t)bh * NC_ * 4096) + qt * 256 + tid;
    ushort4* Ob = (ushort4*)(STb + (size_t)bh * NC_ * 4096) + qt * 256 + tid;
    float4 v[16];
#pragma unroll
    for (int c = 0; c < NC_; ++c) v[c] = Sb[c * 1024];
    float4 acc = make_float4(0.f, 0.f, 0.f, 0.f);
#pragma unroll
    for (int c = 0; c < NC_; ++c) {
      ushort4 o;
      o.x = rnbf(acc.x); o.y = rnbf(acc.y); o.z = rnbf(acc.z); o.w = rnbf(acc.w);
      Ob[c * 1024] = o;
      acc.x += v[c].x; acc.y += v[c].y; acc.z += v[c].z; acc.w += v[c].w;
    }
  } else {
    const int bh = b - 256;
    if (tid < 16) {
      const float4* zpb = (const float4*)(zp + (size_t)bh * NC_ * 64);
      float4* zob = (float4*)(zout + (size_t)bh * NC_ * 64);
      float4 t0[16];
#pragma unroll
      for (int c = 0; c < NC_; ++c) t0[c] = zpb[c * 16 + tid];
      float4 za = make_float4(0.f, 0.f, 0.f, 0.f);
#pragma unroll
      for (int c = 0; c < NC_; ++c) {
        zob[c * 16 + tid] = za;
        za.x += t0[c].x; za.y += t0[c].y;
        za.z += t0[c].z; za.w += t0[c].w;
      }
    }
  }
}

// ---------------------------------------------------------------------------
// Kernel 4 (MFMA): per-chunk output -> y bf16 [B,T,H,D]
// ---------------------------------------------------------------------------
__global__ __launch_bounds__(512, 4) void k_out(
    const ushort* __restrict__ qg, const ushort* __restrict__ kg,
    const ushort* __restrict__ vtg, const ushort* __restrict__ STb,
    const float* __restrict__ zg, ushort* __restrict__ yb) {
  __shared__ __align__(16) ushort k_s[128 * 64];
  __shared__ __align__(16) ushort vT_s[64 * 128];
  __shared__ __align__(16) ushort ST_s[64 * 64];
  __shared__ __align__(16) ushort P_s[128 * 128];
  __shared__ float z_s[64];
  __shared__ float dinter_s[128];
  const int blk = blockIdx.x;
  const int bh = blk >> 4, c = blk & 15;
  const int tid = threadIdx.x;
  const int w = tid >> 6, l = tid & 63;

  const ushort* kbase = kg + ((size_t)bh * T_ + c * CHUNK_) * D_;
  const ushort* vbase = vtg + (size_t)bh * D_ * T_ + c * CHUNK_;
  const ushort* sbase = STb + ((size_t)bh * NC_ + c) * 4096;
  {
    int seg = w, row = seg * 8 + (l >> 3);
    gload_lds16(kbase + (size_t)row * 64 + ((l & 7) ^ (row & 7)) * 8, &k_s[seg * 512]);
    seg = w + 8; row = seg * 8 + (l >> 3);
    gload_lds16(kbase + (size_t)row * 64 + ((l & 7) ^ (row & 7)) * 8, &k_s[seg * 512]);
  }
  {
    int seg = w, row = seg * 4 + (l >> 4);
    gload_lds16(vbase + (size_t)row * T_ + ((l & 15) ^ (row & 7)) * 8, &vT_s[seg * 512]);
    seg = w + 8; row = seg * 4 + (l >> 4);
    gload_lds16(vbase + (size_t)row * T_ + ((l & 15) ^ (row & 7)) * 8, &vT_s[seg * 512]);
  }
  {
    const int seg = w, row = seg * 8 + (l >> 3);
    gload_lds16(sbase + (size_t)row * 64 + ((l & 7) ^ (row & 7)) * 8, &ST_s[seg * 512]);
  }
  if (tid < 64) z_s[tid] = zg[((size_t)bh * NC_ + c) * 64 + tid];
  const int arow = w * 16 + (l & 15);
  const ushort* qrow = qg + ((size_t)bh * T_ + c * CHUNK_ + arow) * D_ + (l >> 4) * 8;
  bf16x8 qf0 = *(const bf16x8*)(qrow);
  bf16x8 qf1 = *(const bf16x8*)(qrow + 32);
  __syncthreads();

  f32x4 sc[8] = {};
#pragma unroll
  for (int jt = 0; jt < 8; ++jt) {
    const int j = jt * 16 + (l & 15);
    const int sw = (j & 7) << 3, g = (l >> 4) * 8;
    bf16x8 b0 = *(const bf16x8*)&k_s[j * 64 + (g ^ sw)];
    bf16x8 b1 = *(const bf16x8*)&k_s[j * 64 + ((g + 32) ^ sw)];
    sc[jt] = __builtin_amdgcn_mfma_f32_16x16x32_bf16(qf0, b0, sc[jt], 0, 0, 0);
    sc[jt] = __builtin_amdgcn_mfma_f32_16x16x32_bf16(qf1, b1, sc[jt], 0, 0, 0);
  }
  const int crow0 = w * 16 + (l >> 4) * 4;
  float rsum[4] = {0.f, 0.f, 0.f, 0.f};
#pragma unroll
  for (int jt = 0; jt < 8; ++jt) {
    const int j = jt * 16 + (l & 15);
#pragma unroll
    for (int jj = 0; jj < 4; ++jj) {
      const int i = crow0 + jj;
      float s = (j <= i) ? sc[jt][jj] : 0.f;
      rsum[jj] += s;
      P_s[i * 128 + (j ^ ((i & 7) << 3))] = rnbf(s);
    }
  }
  float di = 0.f;
#pragma unroll
  for (int jj = 0; jj < 8; ++jj) {
    di = fmaf(bf2f(qf0[jj]), z_s[(l >> 4) * 8 + jj], di);
    di = fmaf(bf2f(qf1[jj]), z_s[32 + (l >> 4) * 8 + jj], di);
  }
  di += __shfl_xor(di, 16);
  di += __shfl_xor(di, 32);
  if (l < 16) dinter_s[w * 16 + l] = di;
#pragma unroll
  for (int jj = 0; jj < 4; ++jj) {
    float r = rsum[jj];
    r += __shfl_xor(r, 1); r += __shfl_xor(r, 2);
    r += __shfl_xor(r, 4); r += __shfl_xor(r, 8);
    rsum[jj] = r;
  }
  __syncthreads();

  f32x4 acc2[4] = {};
#pragma unroll
  for (int et = 0; et < 4; ++et) {
    const int e = et * 16 + (l & 15);
    const int sw = (e & 7) << 3, g = (l >> 4) * 8;
    bf16x8 s0 = *(const bf16x8*)&ST_s[e * 64 + (g ^ sw)];
    bf16x8 s1 = *(const bf16x8*)&ST_s[e * 64 + ((g + 32) ^ sw)];
    acc2[et] = __builtin_amdgcn_mfma_f32_16x16x32_bf16(qf0, s0, acc2[et], 0, 0, 0);
    acc2[et] = __builtin_amdgcn_mfma_f32_16x16x32_bf16(qf1, s1, acc2[et], 0, 0, 0);
  }
  const int prow = w * 16 + (l & 15);
  const int psw = (prow & 7) << 3;
#pragma unroll
  for (int jkt = 0; jkt < 4; ++jkt) {
    bf16x8 pa = *(const bf16x8*)&P_s[prow * 128 + ((jkt * 32 + (l >> 4) * 8) ^ psw)];
#pragma unroll
    for (int et = 0; et < 4; ++et) {
      const int e = et * 16 + (l & 15);
      bf16x8 bv = *(const bf16x8*)&vT_s[e * 128 +
                                        ((jkt * 32 + (l >> 4) * 8) ^ ((e & 7) << 3))];
      acc2[et] = __builtin_amdgcn_mfma_f32_16x16x32_bf16(pa, bv, acc2[et], 0, 0, 0);
    }
  }
  float inv[4];
#pragma unroll
  for (int jj = 0; jj < 4; ++jj)
    inv[jj] = 1.0f / (rsum[jj] + dinter_s[crow0 + jj] + 1e-6f);
  const int b = bh >> 4, h = bh & 15;
#pragma unroll
  for (int et = 0; et < 4; ++et) {
    const int d = et * 16 + (l & 15);
#pragma unroll
    for (int jj = 0; jj < 4; ++jj) {
      const int t = c * CHUNK_ + crow0 + jj;
      yb[((size_t)(b * T_ + t) * H_ + h) * D_ + d] = rnbf(acc2[et][jj] * inv[jj]);
    }
  }
}

// ---------------------------------------------------------------------------
extern "C" void kernel_launch(void* const* d_in, const int* in_sizes, int n_in,
                              void* d_out, int out_size, void* d_ws, size_t ws_size,
                              hipStream_t stream) {
  const float* x = (const float*)d_in[0];
  const float* w_attn = (const float*)d_in[1];
  const float* w_proj = (const float*)d_in[2];
  float* out = (float*)d_out;

  ushort* xb = (ushort*)d_ws;                        // [8192,1024]
  ushort* wab = xb + (size_t)M_ * E_;                // [3072,1024]
  ushort* wpb = wab + (size_t)3 * E_ * E_;           // [1024,1024]
  ushort* qb = wpb + (size_t)E_ * E_;                // [bh][t][d]
  ushort* kbm = qb + (size_t)M_ * E_;                // [bh][t][d]
  ushort* kT = kbm + (size_t)M_ * E_;                // [bh][d][t]
  ushort* vT = kT + (size_t)M_ * E_;                 // [bh][d][t]
  ushort* yb = vT + (size_t)M_ * E_;                 // [B,T,H,D]
  ushort* STb = yb + (size_t)M_ * E_;                // [bh][c][e][d] bf16
  float* Schunk = (float*)(STb + (size_t)BH_ * NC_ * 4096);  // fp32
  float* zpart = Schunk + (size_t)BH_ * NC_ * 4096;  // [bh][c][64]
  float* zout = zpart + (size_t)BH_ * NC_ * 64;      // [bh][c][64]

  k_cvt3<<<12288, 256, 0, stream>>>(x, w_attn, w_proj, xb, wab, wpb);

  hipFuncSetAttribute((const void*)k_qkv4,
                      hipFuncAttributeMaxDynamicSharedMemorySize, 98304);
  hipFuncSetAttribute((const void*)k_proj2,
                      hipFuncAttributeMaxDynamicSharedMemorySize, 49152);

  k_qkv4<<<384, 512, 98304, stream>>>(xb, wab, qb, kbm, kT, vT, zpart);
  k_stats<<<1024, 256, 0, stream>>>(kT, vT, Schunk);
  k_prefix2<<<320, 256, 0, stream>>>(Schunk, STb, zpart, zout);
  k_out<<<1024, 512, 0, stream>>>(qb, kbm, vT, STb, zout, yb);
  k_proj2<<<256, 512, 49152, stream>>>(yb, wpb, out);
}

// Round 11
// 128.750 us; speedup vs baseline: 1.1518x; 1.0895x over previous
//
#include <hip/hip_runtime.h>
#include <math.h>

#define B_ 4
#define T_ 2048
#define E_ 1024
#define H_ 16
#define D_ 64
#define CHUNK_ 128
#define NC_ 16
#define BH_ (B_ * H_)   // 64
#define M_ (B_ * T_)    // 8192

typedef __attribute__((ext_vector_type(8))) short bf16x8;
typedef __attribute__((ext_vector_type(4))) float f32x4;

__device__ __forceinline__ ushort rnbf(float f) {
  unsigned u = __float_as_uint(f);
  unsigned r = (u + 0x7FFFu + ((u >> 16) & 1u)) >> 16;
  return (ushort)r;
}

__device__ __forceinline__ float bf2f(short s) {
  return __uint_as_float(((unsigned)(ushort)s) << 16);
}

__device__ __forceinline__ void gload_lds16(const void* g, void* l) {
  __builtin_amdgcn_global_load_lds(
      (const __attribute__((address_space(1))) unsigned int*)g,
      (__attribute__((address_space(3))) unsigned int*)l, 16, 0, 0);
}

#define VMW(N) do { asm volatile("s_waitcnt vmcnt(" #N ")" ::: "memory"); \
                    __builtin_amdgcn_sched_barrier(0); } while (0)
#define BARR() do { __builtin_amdgcn_s_barrier(); \
                    __builtin_amdgcn_sched_barrier(0); } while (0)

// ---------------------------------------------------------------------------
// fused fp32 -> bf16 conversion for x, w_attn, w_proj (one launch)
// ---------------------------------------------------------------------------
#define N4X_ (M_ * E_ / 4)           // 2097152
#define N4A_ (3 * E_ * E_ / 4)       // 786432
#define N4P_ (E_ * E_ / 4)           // 262144
__global__ __launch_bounds__(256) void k_cvt3(
    const float* __restrict__ x, const float* __restrict__ wa,
    const float* __restrict__ wp, ushort* __restrict__ xb,
    ushort* __restrict__ wab, ushort* __restrict__ wpb) {
  int i = blockIdx.x * 256 + threadIdx.x;
  const float* src;
  ushort* dst;
  int off;
  if (i < N4X_) { src = x; dst = xb; off = i; }
  else if (i < N4X_ + N4A_) { src = wa; dst = wab; off = i - N4X_; }
  else { src = wp; dst = wpb; off = i - (N4X_ + N4A_); }
  float4 v = ((const float4*)src)[off];
  ushort4 o;
  o.x = rnbf(v.x); o.y = rnbf(v.y); o.z = rnbf(v.z); o.w = rnbf(v.w);
  ((ushort4*)dst)[off] = o;
}

// ---------------------------------------------------------------------------
// Pipelined MFMA GEMM core: C 128x256 tile = A[128xK] x B[256xK]^T, K=1024.
// 8 waves (2M x 4N). BK=32 slabs, 3-deep rotation (72 KB LDS, 2 blocks/CU).
// Per phase: VMW(3), barrier, 8 ds_read_b128 (chunk-XOR swizzled), stage
// slot t+2 (safe: slab (t+2)%3 last read at t-1, drained by entry barrier),
// 16 MFMA (setprio-wrapped). This is the proven 844 TF configuration (R6),
// ~94% of the 2-barrier structure ceiling. R9/R10 falsified the 256x256
// deep-pipeline port at this problem shape (grid 384 = 1.5 rounds @ 1
// blk/CU, structural tail). R7 lesson: launch_bounds min-waves stays <=4 —
// (512,6) caps VGPR at ~85 and spills acc (456us, 2GB scratch traffic).
// ---------------------------------------------------------------------------
#define STG(sl_, tt_) { \
  gload_lds16(Asrc + (tt_) * 32, &lds[(sl_) * 4096 + tid * 8]); \
  gload_lds16(Bsrc0 + (tt_) * 32, &lds[12288 + (sl_) * 8192 + tid * 8]); \
  gload_lds16(Bsrc1 + (tt_) * 32, &lds[12288 + (sl_) * 8192 + 4096 + tid * 8]); }

#define LDFRAGS(sl_) \
  const ushort* pa = &lds[(sl_) * 4096 + aOff]; \
  a0 = *(const bf16x8*)pa;          a1 = *(const bf16x8*)(pa + 512); \
  a2 = *(const bf16x8*)(pa + 1024); a3 = *(const bf16x8*)(pa + 1536); \
  const ushort* pb = &lds[12288 + (sl_) * 8192 + bOff]; \
  b0 = *(const bf16x8*)pb;          b1 = *(const bf16x8*)(pb + 512); \
  b2 = *(const bf16x8*)(pb + 1024); b3 = *(const bf16x8*)(pb + 1536);

#define MM(i, j, A_, B_) \
  acc[i][j] = __builtin_amdgcn_mfma_f32_16x16x32_bf16(A_, B_, acc[i][j], 0, 0, 0)
#define MFMA16() do { __builtin_amdgcn_s_setprio(1); \
  MM(0,0,a0,b0); MM(0,1,a0,b1); MM(0,2,a0,b2); MM(0,3,a0,b3); \
  MM(1,0,a1,b0); MM(1,1,a1,b1); MM(1,2,a1,b2); MM(1,3,a1,b3); \
  MM(2,0,a2,b0); MM(2,1,a2,b1); MM(2,2,a2,b2); MM(2,3,a2,b3); \
  MM(3,0,a3,b0); MM(3,1,a3,b1); MM(3,2,a3,b2); MM(3,3,a3,b3); \
  __builtin_amdgcn_s_setprio(0); } while (0)

__device__ __forceinline__ void pipe_gemm(const ushort* __restrict__ Ag,
                                          const ushort* __restrict__ Bg,
                                          ushort* lds, f32x4 acc[4][4]) {
  const int tid = threadIdx.x;
  const int l = tid & 63, wv = tid >> 6;
  const int wm = wv >> 2, wn = wv & 3;
  const int c16 = l & 15, g4 = l >> 4;
  const int gch = (tid & 3) ^ ((tid >> 3) & 3);
  const ushort* Asrc = Ag + (size_t)(tid >> 2) * 1024 + gch * 8;
  const ushort* Bsrc0 = Bg + (size_t)(tid >> 2) * 1024 + gch * 8;
  const ushort* Bsrc1 = Bsrc0 + (size_t)128 * 1024;
  const int xq = (c16 >> 1) & 3;
  const int aOff = (wm * 64 + c16) * 32 + ((g4 ^ xq) << 3);
  const int bOff = (wn * 64 + c16) * 32 + ((g4 ^ xq) << 3);

  STG(0, 0);
  STG(1, 1);
  int sl = 0;
#pragma unroll 3
  for (int t = 0; t < 30; ++t) {
    const int slN = sl ? sl - 1 : 2;  // (sl+2)%3
    VMW(3); BARR();
    bf16x8 a0, a1, a2, a3, b0, b1, b2, b3;
    LDFRAGS(sl);
    STG(slN, t + 2);
    MFMA16();
    sl = (sl == 2) ? 0 : sl + 1;
  }
  {  // t=30, slab 0
    VMW(3); BARR();
    bf16x8 a0, a1, a2, a3, b0, b1, b2, b3;
    LDFRAGS(0);
    MFMA16();
  }
  {  // t=31, slab 1
    VMW(0); BARR();
    bf16x8 a0, a1, a2, a3, b0, b1, b2, b3;
    LDFRAGS(1);
    MFMA16();
  }
}

// ---------------------------------------------------------------------------
// Kernel 1: qkv = x @ w_attn^T; phi on q,k; q/k row-major, kT/vT transposed
// (per-wave LDS transpose), z chunk-partials fused.
// XCD-L2 mapping: xcd = b&7 owns bm slice [xcd*8, xcd*8+8), bm-fastest ->
// A slice (2 MB) L2-resident, B panel shared by co-running bm-blocks.
// ---------------------------------------------------------------------------
__global__ __launch_bounds__(512, 4) void k_qkv2(
    const ushort* __restrict__ xb, const ushort* __restrict__ wab,
    ushort* __restrict__ qg, ushort* __restrict__ kg,
    ushort* __restrict__ ktg, ushort* __restrict__ vtg,
    float* __restrict__ zp) {
  extern __shared__ ushort lds[];
  const int b = blockIdx.x;
  const int xcd = b & 7, idx = b >> 3;     // idx in [0,96)
  const int bm = xcd * 8 + (idx & 7);      // [0,64)
  const int bn = idx >> 3;                 // [0,12)
  const int tid = threadIdx.x;
  const int wv = tid >> 6, l = tid & 63;
  const int wm = wv >> 2, wn = wv & 3;
  const int c16 = l & 15, g4 = l >> 4;

  f32x4 acc[4][4] = {};
  pipe_gemm(xb + (size_t)bm * 128 * 1024, wab + (size_t)bn * 256 * 1024, lds, acc);

  // ---- epilogue ----
  BARR();  // pipeline LDS reads done; LDS reused as transpose buffers
  const int colbase = bn * 256 + wn * 64;
  const int which = colbase >> 10;
  const int h = (colbase & 1023) >> 6;
  const int rowbase = bm * 128 + wm * 64;
  const int bidx = rowbase >> 11;
  const int tbase = rowbase & 2047;
  const size_t bh = (size_t)(bidx * 16 + h);
  ushort* wlds = &lds[wv * 4096];  // per-wave 64d x 64t transpose tile
  float zpart[4] = {0.f, 0.f, 0.f, 0.f};
#pragma unroll
  for (int mf = 0; mf < 4; ++mf) {
#pragma unroll
    for (int nf = 0; nf < 4; ++nf) {
      float o[4];
#pragma unroll
      for (int j = 0; j < 4; ++j) {
        float u = acc[mf][nf][j];
        o[j] = (which < 2) ? ((u > 0.f) ? u + 1.f : expf(u)) : u;  // elu+1
      }
      const int d = nf * 16 + c16;
      if (which == 1) zpart[nf] += o[0] + o[1] + o[2] + o[3];
      if (which <= 1) {
        ushort* dst = (which == 0) ? qg : kg;
        const size_t rb = (bh * 2048 + tbase + mf * 16 + g4 * 4) * 64 + d;
#pragma unroll
        for (int j = 0; j < 4; ++j) dst[rb + (size_t)j * 64] = rnbf(o[j]);
      }
      if (which >= 1) {
        const int tb = (mf * 4 + g4) ^ ((d & 3) << 1);
        ushort4 pk;
        pk.x = rnbf(o[0]); pk.y = rnbf(o[1]); pk.z = rnbf(o[2]); pk.w = rnbf(o[3]);
        *(ushort4*)&wlds[d * 64 + tb * 4] = pk;
      }
    }
  }
  if (which == 1) {
    const int cc = tbase >> 7;
#pragma unroll
    for (int nf = 0; nf < 4; ++nf) {
      float zz = zpart[nf];
      zz += __shfl_xor(zz, 16);
      zz += __shfl_xor(zz, 32);
      if (l < 16) zp[((bh * NC_ + cc) * 2 + wm) * 64 + nf * 16 + l] = zz;
    }
  }
  if (which >= 1) {
    asm volatile("s_waitcnt lgkmcnt(0)" ::: "memory");
    __builtin_amdgcn_sched_barrier(0);
    ushort* tg = (which == 1) ? ktg : vtg;
#pragma unroll
    for (int it = 0; it < 8; ++it) {
      const int d = it * 8 + (l >> 3);
      const int t0 = (l & 7) * 8;
      const int blk = ((l & 7) * 2) ^ ((d & 3) << 1);
      bf16x8 vv_ = *(const bf16x8*)&wlds[d * 64 + blk * 4];
      *(bf16x8*)&tg[(bh * 64 + d) * 2048 + tbase + t0] = vv_;
    }
  }
}

// ---------------------------------------------------------------------------
// Kernel 5: out = y @ w_proj^T, same pipelined core, fp32 epilogue.
// XCD-L2 mapping: per-XCD working set = A 2MB + B 2MB (fits 4MB L2).
// ---------------------------------------------------------------------------
__global__ __launch_bounds__(512, 4) void k_proj2(
    const ushort* __restrict__ yb, const ushort* __restrict__ wpb,
    float* __restrict__ out) {
  extern __shared__ ushort lds[];
  const int b = blockIdx.x;
  const int xcd = b & 7, idx = b >> 3;     // idx in [0,32)
  const int bm = xcd * 8 + (idx & 7);      // [0,64)
  const int bn = idx >> 3;                 // [0,4)
  const int tid = threadIdx.x;
  const int wv = tid >> 6, l = tid & 63;
  const int wm = wv >> 2, wn = wv & 3;
  const int c16 = l & 15, g4 = l >> 4;

  f32x4 acc[4][4] = {};
  pipe_gemm(yb + (size_t)bm * 128 * 1024, wpb + (size_t)bn * 256 * 1024, lds, acc);

  const int rowbase = bm * 128 + wm * 64 + g4 * 4;
  const int colbase = bn * 256 + wn * 64 + c16;
#pragma unroll
  for (int mf = 0; mf < 4; ++mf)
#pragma unroll
    for (int nf = 0; nf < 4; ++nf) {
      const size_t base = (size_t)(rowbase + mf * 16) * 1024 + colbase + nf * 16;
#pragma unroll
      for (int j = 0; j < 4; ++j)
        out[base + (size_t)j * 1024] = acc[mf][nf][j];
    }
}

// ---------------------------------------------------------------------------
// Kernel 2 (MFMA): per-chunk  ST[e][d] = sum_t v[t][e] k[t][d]  (fp32 out)
// ---------------------------------------------------------------------------
__global__ __launch_bounds__(256) void k_stats(const ushort* __restrict__ ktg,
                                               const ushort* __restrict__ vtg,
                                               float* __restrict__ Sc) {
  __shared__ __align__(16) ushort kT_s[64 * 128], vT_s[64 * 128];
  const int blk = blockIdx.x;
  const int bh = blk >> 4, c = blk & 15;
  const int tid = threadIdx.x;
  const int w = tid >> 6, l = tid & 63;
  const ushort* ktb = ktg + (size_t)bh * D_ * T_ + c * CHUNK_;
  const ushort* vtb = vtg + (size_t)bh * D_ * T_ + c * CHUNK_;
#pragma unroll
  for (int s2 = 0; s2 < 4; ++s2) {
    const int seg = w * 4 + s2;
    const int row = seg * 4 + (l >> 4);
    const int sb = ((l & 15) ^ (row & 7)) * 8;
    gload_lds16(ktb + (size_t)row * T_ + sb, &kT_s[seg * 512]);
    gload_lds16(vtb + (size_t)row * T_ + sb, &vT_s[seg * 512]);
  }
  __syncthreads();
  const int wr = w >> 1, wc = w & 1;
  f32x4 acc[2][2] = {};
#pragma unroll
  for (int kt = 0; kt < 4; ++kt) {
    const int g = kt * 32 + (l >> 4) * 8;
    bf16x8 av[2], bk[2];
#pragma unroll
    for (int rt = 0; rt < 2; ++rt) {
      const int e = wr * 32 + rt * 16 + (l & 15);
      av[rt] = *(const bf16x8*)&vT_s[e * 128 + (g ^ ((e & 7) << 3))];
    }
#pragma unroll
    for (int ct = 0; ct < 2; ++ct) {
      const int d = wc * 32 + ct * 16 + (l & 15);
      bk[ct] = *(const bf16x8*)&kT_s[d * 128 + (g ^ ((d & 7) << 3))];
    }
#pragma unroll
    for (int rt = 0; rt < 2; ++rt)
#pragma unroll
      for (int ct = 0; ct < 2; ++ct)
        acc[rt][ct] = __builtin_amdgcn_mfma_f32_16x16x32_bf16(av[rt], bk[ct],
                                                              acc[rt][ct], 0, 0, 0);
  }
  float* So = Sc + (size_t)blk * 4096;
#pragma unroll
  for (int rt = 0; rt < 2; ++rt)
#pragma unroll
    for (int ct = 0; ct < 2; ++ct)
#pragma unroll
      for (int jj = 0; jj < 4; ++jj)
        So[(wr * 32 + rt * 16 + (l >> 4) * 4 + jj) * 64 + wc * 32 + ct * 16 + (l & 15)] =
            acc[rt][ct][jj];
}

// ---------------------------------------------------------------------------
// Kernel 3: exclusive prefix over 16 chunks, parallelized.
// blocks 0..255: (bh, quarter) S-scan; blocks 256..319: z-scan per bh
// (z partials come in 2 halves per chunk from k_qkv2's wm split).
// ---------------------------------------------------------------------------
__global__ __launch_bounds__(256) void k_prefix2(const float* __restrict__ Sc,
                                                 ushort* __restrict__ STb,
                                                 const float* __restrict__ zp,
                                                 float* __restrict__ zout) {
  const int b = blockIdx.x;
  const int tid = threadIdx.x;
  if (b < 256) {
    const int bh = b >> 2, qt = b & 3;
    const float4* Sb = (const float4*)(Sc + (size_t)bh * NC_ * 4096) + qt * 256 + tid;
    ushort4* Ob = (ushort4*)(STb + (size_t)bh * NC_ * 4096) + qt * 256 + tid;
    float4 v[16];
#pragma unroll
    for (int c = 0; c < NC_; ++c) v[c] = Sb[c * 1024];
    float4 acc = make_float4(0.f, 0.f, 0.f, 0.f);
#pragma unroll
    for (int c = 0; c < NC_; ++c) {
      ushort4 o;
      o.x = rnbf(acc.x); o.y = rnbf(acc.y); o.z = rnbf(acc.z); o.w = rnbf(acc.w);
      Ob[c * 1024] = o;
      acc.x += v[c].x; acc.y += v[c].y; acc.z += v[c].z; acc.w += v[c].w;
    }
  } else {
    const int bh = b - 256;
    if (tid < 16) {
      const float4* zpb = (const float4*)(zp + (size_t)bh * NC_ * 128);
      float4* zob = (float4*)(zout + (size_t)bh * NC_ * 64);
      float4 t0[16], t1[16];
#pragma unroll
      for (int c = 0; c < NC_; ++c) {
        t0[c] = zpb[c * 32 + tid];
        t1[c] = zpb[c * 32 + 16 + tid];
      }
      float4 za = make_float4(0.f, 0.f, 0.f, 0.f);
#pragma unroll
      for (int c = 0; c < NC_; ++c) {
        zob[c * 16 + tid] = za;
        za.x += t0[c].x + t1[c].x; za.y += t0[c].y + t1[c].y;
        za.z += t0[c].z + t1[c].z; za.w += t0[c].w + t1[c].w;
      }
    }
  }
}

// ---------------------------------------------------------------------------
// Kernel 4 (MFMA): per-chunk output -> y bf16 [B,T,H,D]
// ---------------------------------------------------------------------------
__global__ __launch_bounds__(512, 4) void k_out(
    const ushort* __restrict__ qg, const ushort* __restrict__ kg,
    const ushort* __restrict__ vtg, const ushort* __restrict__ STb,
    const float* __restrict__ zg, ushort* __restrict__ yb) {
  __shared__ __align__(16) ushort k_s[128 * 64];
  __shared__ __align__(16) ushort vT_s[64 * 128];
  __shared__ __align__(16) ushort ST_s[64 * 64];
  __shared__ __align__(16) ushort P_s[128 * 128];
  __shared__ float z_s[64];
  __shared__ float dinter_s[128];
  const int blk = blockIdx.x;
  const int bh = blk >> 4, c = blk & 15;
  const int tid = threadIdx.x;
  const int w = tid >> 6, l = tid & 63;

  const ushort* kbase = kg + ((size_t)bh * T_ + c * CHUNK_) * D_;
  const ushort* vbase = vtg + (size_t)bh * D_ * T_ + c * CHUNK_;
  const ushort* sbase = STb + ((size_t)bh * NC_ + c) * 4096;
  {
    int seg = w, row = seg * 8 + (l >> 3);
    gload_lds16(kbase + (size_t)row * 64 + ((l & 7) ^ (row & 7)) * 8, &k_s[seg * 512]);
    seg = w + 8; row = seg * 8 + (l >> 3);
    gload_lds16(kbase + (size_t)row * 64 + ((l & 7) ^ (row & 7)) * 8, &k_s[seg * 512]);
  }
  {
    int seg = w, row = seg * 4 + (l >> 4);
    gload_lds16(vbase + (size_t)row * T_ + ((l & 15) ^ (row & 7)) * 8, &vT_s[seg * 512]);
    seg = w + 8; row = seg * 4 + (l >> 4);
    gload_lds16(vbase + (size_t)row * T_ + ((l & 15) ^ (row & 7)) * 8, &vT_s[seg * 512]);
  }
  {
    const int seg = w, row = seg * 8 + (l >> 3);
    gload_lds16(sbase + (size_t)row * 64 + ((l & 7) ^ (row & 7)) * 8, &ST_s[seg * 512]);
  }
  if (tid < 64) z_s[tid] = zg[((size_t)bh * NC_ + c) * 64 + tid];
  const int arow = w * 16 + (l & 15);
  const ushort* qrow = qg + ((size_t)bh * T_ + c * CHUNK_ + arow) * D_ + (l >> 4) * 8;
  bf16x8 qf0 = *(const bf16x8*)(qrow);
  bf16x8 qf1 = *(const bf16x8*)(qrow + 32);
  __syncthreads();

  f32x4 sc[8] = {};
#pragma unroll
  for (int jt = 0; jt < 8; ++jt) {
    const int j = jt * 16 + (l & 15);
    const int sw = (j & 7) << 3, g = (l >> 4) * 8;
    bf16x8 b0 = *(const bf16x8*)&k_s[j * 64 + (g ^ sw)];
    bf16x8 b1 = *(const bf16x8*)&k_s[j * 64 + ((g + 32) ^ sw)];
    sc[jt] = __builtin_amdgcn_mfma_f32_16x16x32_bf16(qf0, b0, sc[jt], 0, 0, 0);
    sc[jt] = __builtin_amdgcn_mfma_f32_16x16x32_bf16(qf1, b1, sc[jt], 0, 0, 0);
  }
  const int crow0 = w * 16 + (l >> 4) * 4;
  float rsum[4] = {0.f, 0.f, 0.f, 0.f};
#pragma unroll
  for (int jt = 0; jt < 8; ++jt) {
    const int j = jt * 16 + (l & 15);
#pragma unroll
    for (int jj = 0; jj < 4; ++jj) {
      const int i = crow0 + jj;
      float s = (j <= i) ? sc[jt][jj] : 0.f;
      rsum[jj] += s;
      P_s[i * 128 + (j ^ ((i & 7) << 3))] = rnbf(s);
    }
  }
  float di = 0.f;
#pragma unroll
  for (int jj = 0; jj < 8; ++jj) {
    di = fmaf(bf2f(qf0[jj]), z_s[(l >> 4) * 8 + jj], di);
    di = fmaf(bf2f(qf1[jj]), z_s[32 + (l >> 4) * 8 + jj], di);
  }
  di += __shfl_xor(di, 16);
  di += __shfl_xor(di, 32);
  if (l < 16) dinter_s[w * 16 + l] = di;
#pragma unroll
  for (int jj = 0; jj < 4; ++jj) {
    float r = rsum[jj];
    r += __shfl_xor(r, 1); r += __shfl_xor(r, 2);
    r += __shfl_xor(r, 4); r += __shfl_xor(r, 8);
    rsum[jj] = r;
  }
  __syncthreads();

  f32x4 acc2[4] = {};
#pragma unroll
  for (int et = 0; et < 4; ++et) {
    const int e = et * 16 + (l & 15);
    const int sw = (e & 7) << 3, g = (l >> 4) * 8;
    bf16x8 s0 = *(const bf16x8*)&ST_s[e * 64 + (g ^ sw)];
    bf16x8 s1 = *(const bf16x8*)&ST_s[e * 64 + ((g + 32) ^ sw)];
    acc2[et] = __builtin_amdgcn_mfma_f32_16x16x32_bf16(qf0, s0, acc2[et], 0, 0, 0);
    acc2[et] = __builtin_amdgcn_mfma_f32_16x16x32_bf16(qf1, s1, acc2[et], 0, 0, 0);
  }
  const int prow = w * 16 + (l & 15);
  const int psw = (prow & 7) << 3;
#pragma unroll
  for (int jkt = 0; jkt < 4; ++jkt) {
    bf16x8 pa = *(const bf16x8*)&P_s[prow * 128 + ((jkt * 32 + (l >> 4) * 8) ^ psw)];
#pragma unroll
    for (int et = 0; et < 4; ++et) {
      const int e = et * 16 + (l & 15);
      bf16x8 bv = *(const bf16x8*)&vT_s[e * 128 +
                                        ((jkt * 32 + (l >> 4) * 8) ^ ((e & 7) << 3))];
      acc2[et] = __builtin_amdgcn_mfma_f32_16x16x32_bf16(pa, bv, acc2[et], 0, 0, 0);
    }
  }
  float inv[4];
#pragma unroll
  for (int jj = 0; jj < 4; ++jj)
    inv[jj] = 1.0f / (rsum[jj] + dinter_s[crow0 + jj] + 1e-6f);
  const int b = bh >> 4, h = bh & 15;
#pragma unroll
  for (int et = 0; et < 4; ++et) {
    const int d = et * 16 + (l & 15);
#pragma unroll
    for (int jj = 0; jj < 4; ++jj) {
      const int t = c * CHUNK_ + crow0 + jj;
      yb[((size_t)(b * T_ + t) * H_ + h) * D_ + d] = rnbf(acc2[et][jj] * inv[jj]);
    }
  }
}

// ---------------------------------------------------------------------------
extern "C" void kernel_launch(void* const* d_in, const int* in_sizes, int n_in,
                              void* d_out, int out_size, void* d_ws, size_t ws_size,
                              hipStream_t stream) {
  const float* x = (const float*)d_in[0];
  const float* w_attn = (const float*)d_in[1];
  const float* w_proj = (const float*)d_in[2];
  float* out = (float*)d_out;

  ushort* xb = (ushort*)d_ws;                        // [8192,1024]
  ushort* wab = xb + (size_t)M_ * E_;                // [3072,1024]
  ushort* wpb = wab + (size_t)3 * E_ * E_;           // [1024,1024]
  ushort* qb = wpb + (size_t)E_ * E_;                // [bh][t][d]
  ushort* kbm = qb + (size_t)M_ * E_;                // [bh][t][d]
  ushort* kT = kbm + (size_t)M_ * E_;                // [bh][d][t]
  ushort* vT = kT + (size_t)M_ * E_;                 // [bh][d][t]
  ushort* yb = vT + (size_t)M_ * E_;                 // [B,T,H,D]
  ushort* STb = yb + (size_t)M_ * E_;                // [bh][c][e][d] bf16
  float* Schunk = (float*)(STb + (size_t)BH_ * NC_ * 4096);  // fp32
  float* zpart = Schunk + (size_t)BH_ * NC_ * 4096;  // [bh][c][2][64]
  float* zout = zpart + (size_t)BH_ * NC_ * 2 * 64;  // [bh][c][64]

  k_cvt3<<<12288, 256, 0, stream>>>(x, w_attn, w_proj, xb, wab, wpb);

  hipFuncSetAttribute((const void*)k_qkv2,
                      hipFuncAttributeMaxDynamicSharedMemorySize, 73728);
  hipFuncSetAttribute((const void*)k_proj2,
                      hipFuncAttributeMaxDynamicSharedMemorySize, 73728);

  k_qkv2<<<768, 512, 73728, stream>>>(xb, wab, qb, kbm, kT, vT, zpart);
  k_stats<<<1024, 256, 0, stream>>>(kT, vT, Schunk);
  k_prefix2<<<320, 256, 0, stream>>>(Schunk, STb, zpart, zout);
  k_out<<<1024, 512, 0, stream>>>(qb, kbm, vT, STb, zout, yb);
  k_proj2<<<256, 512, 73728, stream>>>(yb, wpb, out);
}

// Round 12
// 128.572 us; speedup vs baseline: 1.1534x; 1.0014x over previous
//
#include <hip/hip_runtime.h>
#include <math.h>

#define B_ 4
#define T_ 2048
#define E_ 1024
#define H_ 16
#define D_ 64
#define CHUNK_ 128
#define NC_ 16
#define BH_ (B_ * H_)   // 64
#define M_ (B_ * T_)    // 8192

typedef __attribute__((ext_vector_type(8))) short bf16x8;
typedef __attribute__((ext_vector_type(4))) float f32x4;

__device__ __forceinline__ ushort rnbf(float f) {
  unsigned u = __float_as_uint(f);
  unsigned r = (u + 0x7FFFu + ((u >> 16) & 1u)) >> 16;
  return (ushort)r;
}

__device__ __forceinline__ float bf2f(short s) {
  return __uint_as_float(((unsigned)(ushort)s) << 16);
}

__device__ __forceinline__ void gload_lds16(const void* g, void* l) {
  __builtin_amdgcn_global_load_lds(
      (const __attribute__((address_space(1))) unsigned int*)g,
      (__attribute__((address_space(3))) unsigned int*)l, 16, 0, 0);
}

#define VMW(N) do { asm volatile("s_waitcnt vmcnt(" #N ")" ::: "memory"); \
                    __builtin_amdgcn_sched_barrier(0); } while (0)
#define BARR() do { __builtin_amdgcn_s_barrier(); \
                    __builtin_amdgcn_sched_barrier(0); } while (0)
#define LGK0() do { asm volatile("s_waitcnt lgkmcnt(0)" ::: "memory"); \
                    __builtin_amdgcn_sched_barrier(0); } while (0)

// ---------------------------------------------------------------------------
// fused fp32 -> bf16 conversion for x, w_attn, w_proj (one launch)
// ---------------------------------------------------------------------------
#define N4X_ (M_ * E_ / 4)           // 2097152
#define N4A_ (3 * E_ * E_ / 4)       // 786432
#define N4P_ (E_ * E_ / 4)           // 262144
__global__ __launch_bounds__(256) void k_cvt3(
    const float* __restrict__ x, const float* __restrict__ wa,
    const float* __restrict__ wp, ushort* __restrict__ xb,
    ushort* __restrict__ wab, ushort* __restrict__ wpb) {
  int i = blockIdx.x * 256 + threadIdx.x;
  const float* src;
  ushort* dst;
  int off;
  if (i < N4X_) { src = x; dst = xb; off = i; }
  else if (i < N4X_ + N4A_) { src = wa; dst = wab; off = i - N4X_; }
  else { src = wp; dst = wpb; off = i - (N4X_ + N4A_); }
  float4 v = ((const float4*)src)[off];
  ushort4 o;
  o.x = rnbf(v.x); o.y = rnbf(v.y); o.z = rnbf(v.z); o.w = rnbf(v.w);
  ((ushort4*)dst)[off] = o;
}

// ---------------------------------------------------------------------------
// Pipelined MFMA GEMM core: C 128x256 tile = A[128xK] x B[256xK]^T, K=1024.
// 8 waves (2M x 4N). BK=32 slabs, 3-deep rotation (72 KB LDS, 2 blocks/CU).
// Per phase: VMW(3), barrier, 8 ds_read_b128 (chunk-XOR swizzled), stage
// slot t+2 (safe: slab (t+2)%3 last read at t-1, drained by entry barrier),
// 16 MFMA (setprio-wrapped). Proven 844 TF configuration (R6/R11), ~94% of
// the 2-barrier structure ceiling. R9/R10 falsified the 256x256 deep
// pipeline at this shape (grid 384 = 1.5 rounds @ 1 blk/CU tail). R7 lesson:
// launch_bounds min-waves stays <=4 — (512,6) caps VGPR ~85, spills acc.
// ---------------------------------------------------------------------------
#define STG(sl_, tt_) { \
  gload_lds16(Asrc + (tt_) * 32, &lds[(sl_) * 4096 + tid * 8]); \
  gload_lds16(Bsrc0 + (tt_) * 32, &lds[12288 + (sl_) * 8192 + tid * 8]); \
  gload_lds16(Bsrc1 + (tt_) * 32, &lds[12288 + (sl_) * 8192 + 4096 + tid * 8]); }

#define LDFRAGS(sl_) \
  const ushort* pa = &lds[(sl_) * 4096 + aOff]; \
  a0 = *(const bf16x8*)pa;          a1 = *(const bf16x8*)(pa + 512); \
  a2 = *(const bf16x8*)(pa + 1024); a3 = *(const bf16x8*)(pa + 1536); \
  const ushort* pb = &lds[12288 + (sl_) * 8192 + bOff]; \
  b0 = *(const bf16x8*)pb;          b1 = *(const bf16x8*)(pb + 512); \
  b2 = *(const bf16x8*)(pb + 1024); b3 = *(const bf16x8*)(pb + 1536);

#define MM(i, j, A_, B_) \
  acc[i][j] = __builtin_amdgcn_mfma_f32_16x16x32_bf16(A_, B_, acc[i][j], 0, 0, 0)
#define MFMA16() do { __builtin_amdgcn_s_setprio(1); \
  MM(0,0,a0,b0); MM(0,1,a0,b1); MM(0,2,a0,b2); MM(0,3,a0,b3); \
  MM(1,0,a1,b0); MM(1,1,a1,b1); MM(1,2,a1,b2); MM(1,3,a1,b3); \
  MM(2,0,a2,b0); MM(2,1,a2,b1); MM(2,2,a2,b2); MM(2,3,a2,b3); \
  MM(3,0,a3,b0); MM(3,1,a3,b1); MM(3,2,a3,b2); MM(3,3,a3,b3); \
  __builtin_amdgcn_s_setprio(0); } while (0)

__device__ __forceinline__ void pipe_gemm(const ushort* __restrict__ Ag,
                                          const ushort* __restrict__ Bg,
                                          ushort* lds, f32x4 acc[4][4]) {
  const int tid = threadIdx.x;
  const int l = tid & 63, wv = tid >> 6;
  const int wm = wv >> 2, wn = wv & 3;
  const int c16 = l & 15, g4 = l >> 4;
  const int gch = (tid & 3) ^ ((tid >> 3) & 3);
  const ushort* Asrc = Ag + (size_t)(tid >> 2) * 1024 + gch * 8;
  const ushort* Bsrc0 = Bg + (size_t)(tid >> 2) * 1024 + gch * 8;
  const ushort* Bsrc1 = Bsrc0 + (size_t)128 * 1024;
  const int xq = (c16 >> 1) & 3;
  const int aOff = (wm * 64 + c16) * 32 + ((g4 ^ xq) << 3);
  const int bOff = (wn * 64 + c16) * 32 + ((g4 ^ xq) << 3);

  STG(0, 0);
  STG(1, 1);
  int sl = 0;
#pragma unroll 3
  for (int t = 0; t < 30; ++t) {
    const int slN = sl ? sl - 1 : 2;  // (sl+2)%3
    VMW(3); BARR();
    bf16x8 a0, a1, a2, a3, b0, b1, b2, b3;
    LDFRAGS(sl);
    STG(slN, t + 2);
    MFMA16();
    sl = (sl == 2) ? 0 : sl + 1;
  }
  {  // t=30, slab 0
    VMW(3); BARR();
    bf16x8 a0, a1, a2, a3, b0, b1, b2, b3;
    LDFRAGS(0);
    MFMA16();
  }
  {  // t=31, slab 1
    VMW(0); BARR();
    bf16x8 a0, a1, a2, a3, b0, b1, b2, b3;
    LDFRAGS(1);
    MFMA16();
  }
}

// ---------------------------------------------------------------------------
// Kernel 1: qkv = x @ w_attn^T; phi on q,k; q/k row-major, kT/vT transposed
// (per-wave LDS transpose), z chunk-partials fused.
// XCD-L2 mapping: xcd = b&7 owns bm slice [xcd*8, xcd*8+8), bm-fastest ->
// A slice (2 MB) L2-resident, B panel shared by co-running bm-blocks.
// ---------------------------------------------------------------------------
__global__ __launch_bounds__(512, 4) void k_qkv2(
    const ushort* __restrict__ xb, const ushort* __restrict__ wab,
    ushort* __restrict__ qg, ushort* __restrict__ kg,
    ushort* __restrict__ ktg, ushort* __restrict__ vtg,
    float* __restrict__ zp) {
  extern __shared__ ushort lds[];
  const int b = blockIdx.x;
  const int xcd = b & 7, idx = b >> 3;     // idx in [0,96)
  const int bm = xcd * 8 + (idx & 7);      // [0,64)
  const int bn = idx >> 3;                 // [0,12)
  const int tid = threadIdx.x;
  const int wv = tid >> 6, l = tid & 63;
  const int wm = wv >> 2, wn = wv & 3;
  const int c16 = l & 15, g4 = l >> 4;

  f32x4 acc[4][4] = {};
  pipe_gemm(xb + (size_t)bm * 128 * 1024, wab + (size_t)bn * 256 * 1024, lds, acc);

  // ---- epilogue ----
  BARR();  // pipeline LDS reads done; LDS reused as transpose buffers
  const int colbase = bn * 256 + wn * 64;
  const int which = colbase >> 10;
  const int h = (colbase & 1023) >> 6;
  const int rowbase = bm * 128 + wm * 64;
  const int bidx = rowbase >> 11;
  const int tbase = rowbase & 2047;
  const size_t bh = (size_t)(bidx * 16 + h);
  ushort* wlds = &lds[wv * 4096];  // per-wave 64d x 64t transpose tile
  float zpart[4] = {0.f, 0.f, 0.f, 0.f};
#pragma unroll
  for (int mf = 0; mf < 4; ++mf) {
#pragma unroll
    for (int nf = 0; nf < 4; ++nf) {
      float o[4];
#pragma unroll
      for (int j = 0; j < 4; ++j) {
        float u = acc[mf][nf][j];
        o[j] = (which < 2) ? ((u > 0.f) ? u + 1.f : expf(u)) : u;  // elu+1
      }
      const int d = nf * 16 + c16;
      if (which == 1) zpart[nf] += o[0] + o[1] + o[2] + o[3];
      if (which <= 1) {
        ushort* dst = (which == 0) ? qg : kg;
        const size_t rb = (bh * 2048 + tbase + mf * 16 + g4 * 4) * 64 + d;
#pragma unroll
        for (int j = 0; j < 4; ++j) dst[rb + (size_t)j * 64] = rnbf(o[j]);
      }
      if (which >= 1) {
        const int tb = (mf * 4 + g4) ^ ((d & 3) << 1);
        ushort4 pk;
        pk.x = rnbf(o[0]); pk.y = rnbf(o[1]); pk.z = rnbf(o[2]); pk.w = rnbf(o[3]);
        *(ushort4*)&wlds[d * 64 + tb * 4] = pk;
      }
    }
  }
  if (which == 1) {
    const int cc = tbase >> 7;
#pragma unroll
    for (int nf = 0; nf < 4; ++nf) {
      float zz = zpart[nf];
      zz += __shfl_xor(zz, 16);
      zz += __shfl_xor(zz, 32);
      if (l < 16) zp[((bh * NC_ + cc) * 2 + wm) * 64 + nf * 16 + l] = zz;
    }
  }
  if (which >= 1) {
    asm volatile("s_waitcnt lgkmcnt(0)" ::: "memory");
    __builtin_amdgcn_sched_barrier(0);
    ushort* tg = (which == 1) ? ktg : vtg;
#pragma unroll
    for (int it = 0; it < 8; ++it) {
      const int d = it * 8 + (l >> 3);
      const int t0 = (l & 7) * 8;
      const int blk = ((l & 7) * 2) ^ ((d & 3) << 1);
      bf16x8 vv_ = *(const bf16x8*)&wlds[d * 64 + blk * 4];
      *(bf16x8*)&tg[(bh * 64 + d) * 2048 + tbase + t0] = vv_;
    }
  }
}

// ---------------------------------------------------------------------------
// Kernel 5: out = y @ w_proj^T, same pipelined core, fp32 epilogue.
// XCD-L2 mapping: per-XCD working set = A 2MB + B 2MB (fits 4MB L2).
// ---------------------------------------------------------------------------
__global__ __launch_bounds__(512, 4) void k_proj2(
    const ushort* __restrict__ yb, const ushort* __restrict__ wpb,
    float* __restrict__ out) {
  extern __shared__ ushort lds[];
  const int b = blockIdx.x;
  const int xcd = b & 7, idx = b >> 3;     // idx in [0,32)
  const int bm = xcd * 8 + (idx & 7);      // [0,64)
  const int bn = idx >> 3;                 // [0,4)
  const int tid = threadIdx.x;
  const int wv = tid >> 6, l = tid & 63;
  const int wm = wv >> 2, wn = wv & 3;
  const int c16 = l & 15, g4 = l >> 4;

  f32x4 acc[4][4] = {};
  pipe_gemm(yb + (size_t)bm * 128 * 1024, wpb + (size_t)bn * 256 * 1024, lds, acc);

  const int rowbase = bm * 128 + wm * 64 + g4 * 4;
  const int colbase = bn * 256 + wn * 64 + c16;
#pragma unroll
  for (int mf = 0; mf < 4; ++mf)
#pragma unroll
    for (int nf = 0; nf < 4; ++nf) {
      const size_t base = (size_t)(rowbase + mf * 16) * 1024 + colbase + nf * 16;
#pragma unroll
      for (int j = 0; j < 4; ++j)
        out[base + (size_t)j * 1024] = acc[mf][nf][j];
    }
}

// ---------------------------------------------------------------------------
// Kernel 2 (MFMA): per-chunk  ST[e][d] = sum_t v[t][e] k[t][d]  (fp32 out)
// ---------------------------------------------------------------------------
__global__ __launch_bounds__(256) void k_stats(const ushort* __restrict__ ktg,
                                               const ushort* __restrict__ vtg,
                                               float* __restrict__ Sc) {
  __shared__ __align__(16) ushort kT_s[64 * 128], vT_s[64 * 128];
  const int blk = blockIdx.x;
  const int bh = blk >> 4, c = blk & 15;
  const int tid = threadIdx.x;
  const int w = tid >> 6, l = tid & 63;
  const ushort* ktb = ktg + (size_t)bh * D_ * T_ + c * CHUNK_;
  const ushort* vtb = vtg + (size_t)bh * D_ * T_ + c * CHUNK_;
#pragma unroll
  for (int s2 = 0; s2 < 4; ++s2) {
    const int seg = w * 4 + s2;
    const int row = seg * 4 + (l >> 4);
    const int sb = ((l & 15) ^ (row & 7)) * 8;
    gload_lds16(ktb + (size_t)row * T_ + sb, &kT_s[seg * 512]);
    gload_lds16(vtb + (size_t)row * T_ + sb, &vT_s[seg * 512]);
  }
  __syncthreads();
  const int wr = w >> 1, wc = w & 1;
  f32x4 acc[2][2] = {};
#pragma unroll
  for (int kt = 0; kt < 4; ++kt) {
    const int g = kt * 32 + (l >> 4) * 8;
    bf16x8 av[2], bk[2];
#pragma unroll
    for (int rt = 0; rt < 2; ++rt) {
      const int e = wr * 32 + rt * 16 + (l & 15);
      av[rt] = *(const bf16x8*)&vT_s[e * 128 + (g ^ ((e & 7) << 3))];
    }
#pragma unroll
    for (int ct = 0; ct < 2; ++ct) {
      const int d = wc * 32 + ct * 16 + (l & 15);
      bk[ct] = *(const bf16x8*)&kT_s[d * 128 + (g ^ ((d & 7) << 3))];
    }
#pragma unroll
    for (int rt = 0; rt < 2; ++rt)
#pragma unroll
      for (int ct = 0; ct < 2; ++ct)
        acc[rt][ct] = __builtin_amdgcn_mfma_f32_16x16x32_bf16(av[rt], bk[ct],
                                                              acc[rt][ct], 0, 0, 0);
  }
  float* So = Sc + (size_t)blk * 4096;
#pragma unroll
  for (int rt = 0; rt < 2; ++rt)
#pragma unroll
    for (int ct = 0; ct < 2; ++ct)
#pragma unroll
      for (int jj = 0; jj < 4; ++jj)
        So[(wr * 32 + rt * 16 + (l >> 4) * 4 + jj) * 64 + wc * 32 + ct * 16 + (l & 15)] =
            acc[rt][ct][jj];
}

// ---------------------------------------------------------------------------
// Kernel 3: exclusive prefix over 16 chunks, parallelized.
// blocks 0..255: (bh, quarter) S-scan; blocks 256..319: z-scan per bh
// (z partials come in 2 halves per chunk from k_qkv2's wm split).
// ---------------------------------------------------------------------------
__global__ __launch_bounds__(256) void k_prefix2(const float* __restrict__ Sc,
                                                 ushort* __restrict__ STb,
                                                 const float* __restrict__ zp,
                                                 float* __restrict__ zout) {
  const int b = blockIdx.x;
  const int tid = threadIdx.x;
  if (b < 256) {
    const int bh = b >> 2, qt = b & 3;
    const float4* Sb = (const float4*)(Sc + (size_t)bh * NC_ * 4096) + qt * 256 + tid;
    ushort4* Ob = (ushort4*)(STb + (size_t)bh * NC_ * 4096) + qt * 256 + tid;
    float4 v[16];
#pragma unroll
    for (int c = 0; c < NC_; ++c) v[c] = Sb[c * 1024];
    float4 acc = make_float4(0.f, 0.f, 0.f, 0.f);
#pragma unroll
    for (int c = 0; c < NC_; ++c) {
      ushort4 o;
      o.x = rnbf(acc.x); o.y = rnbf(acc.y); o.z = rnbf(acc.z); o.w = rnbf(acc.w);
      Ob[c * 1024] = o;
      acc.x += v[c].x; acc.y += v[c].y; acc.z += v[c].z; acc.w += v[c].w;
    }
  } else {
    const int bh = b - 256;
    if (tid < 16) {
      const float4* zpb = (const float4*)(zp + (size_t)bh * NC_ * 128);
      float4* zob = (float4*)(zout + (size_t)bh * NC_ * 64);
      float4 t0[16], t1[16];
#pragma unroll
      for (int c = 0; c < NC_; ++c) {
        t0[c] = zpb[c * 32 + tid];
        t1[c] = zpb[c * 32 + 16 + tid];
      }
      float4 za = make_float4(0.f, 0.f, 0.f, 0.f);
#pragma unroll
      for (int c = 0; c < NC_; ++c) {
        zob[c * 16 + tid] = za;
        za.x += t0[c].x + t1[c].x; za.y += t0[c].y + t1[c].y;
        za.z += t0[c].z + t1[c].z; za.w += t0[c].w + t1[c].w;
      }
    }
  }
}

// ---------------------------------------------------------------------------
// Kernel 4 (MFMA): per-chunk output -> y bf16 [B,T,H,D].
// CAUSAL-AWARE (R12): wave w owns q-rows w*16..w*16+15 and only computes
// key blocks jt <= w (QK^T: 2(w+1) MFMA vs 16; PV: 4(w/2+1) vs 16; avg
// -33% MFMA). Even waves zero-fill the jt=w+1 P_s strip so the boundary
// 32-wide PV block is fully defined (swizzle is a within-row bijection).
// P_s/dinter_s are wave-local (rows w*16..+15) -> the old second
// __syncthreads is replaced by a wave-level lgkmcnt(0) fence (rule #18),
// so imbalanced waves run free instead of lockstepping to wave 7.
// ---------------------------------------------------------------------------
__global__ __launch_bounds__(512, 4) void k_out(
    const ushort* __restrict__ qg, const ushort* __restrict__ kg,
    const ushort* __restrict__ vtg, const ushort* __restrict__ STb,
    const float* __restrict__ zg, ushort* __restrict__ yb) {
  __shared__ __align__(16) ushort k_s[128 * 64];
  __shared__ __align__(16) ushort vT_s[64 * 128];
  __shared__ __align__(16) ushort ST_s[64 * 64];
  __shared__ __align__(16) ushort P_s[128 * 128];
  __shared__ float z_s[64];
  __shared__ float dinter_s[128];
  const int blk = blockIdx.x;
  const int bh = blk >> 4, c = blk & 15;
  const int tid = threadIdx.x;
  const int w = tid >> 6, l = tid & 63;

  const ushort* kbase = kg + ((size_t)bh * T_ + c * CHUNK_) * D_;
  const ushort* vbase = vtg + (size_t)bh * D_ * T_ + c * CHUNK_;
  const ushort* sbase = STb + ((size_t)bh * NC_ + c) * 4096;
  {
    int seg = w, row = seg * 8 + (l >> 3);
    gload_lds16(kbase + (size_t)row * 64 + ((l & 7) ^ (row & 7)) * 8, &k_s[seg * 512]);
    seg = w + 8; row = seg * 8 + (l >> 3);
    gload_lds16(kbase + (size_t)row * 64 + ((l & 7) ^ (row & 7)) * 8, &k_s[seg * 512]);
  }
  {
    int seg = w, row = seg * 4 + (l >> 4);
    gload_lds16(vbase + (size_t)row * T_ + ((l & 15) ^ (row & 7)) * 8, &vT_s[seg * 512]);
    seg = w + 8; row = seg * 4 + (l >> 4);
    gload_lds16(vbase + (size_t)row * T_ + ((l & 15) ^ (row & 7)) * 8, &vT_s[seg * 512]);
  }
  {
    const int seg = w, row = seg * 8 + (l >> 3);
    gload_lds16(sbase + (size_t)row * 64 + ((l & 7) ^ (row & 7)) * 8, &ST_s[seg * 512]);
  }
  if (tid < 64) z_s[tid] = zg[((size_t)bh * NC_ + c) * 64 + tid];
  const int arow = w * 16 + (l & 15);
  const ushort* qrow = qg + ((size_t)bh * T_ + c * CHUNK_ + arow) * D_ + (l >> 4) * 8;
  bf16x8 qf0 = *(const bf16x8*)(qrow);
  bf16x8 qf1 = *(const bf16x8*)(qrow + 32);
  __syncthreads();

  // ---- causal QK^T: wave w only needs key blocks jt <= w ----
  const int crow0 = w * 16 + (l >> 4) * 4;
  float rsum[4] = {0.f, 0.f, 0.f, 0.f};
  for (int jt = 0; jt <= w; ++jt) {
    const int j = jt * 16 + (l & 15);
    const int sw = (j & 7) << 3, g = (l >> 4) * 8;
    bf16x8 b0 = *(const bf16x8*)&k_s[j * 64 + (g ^ sw)];
    bf16x8 b1 = *(const bf16x8*)&k_s[j * 64 + ((g + 32) ^ sw)];
    f32x4 s4 = {0.f, 0.f, 0.f, 0.f};
    s4 = __builtin_amdgcn_mfma_f32_16x16x32_bf16(qf0, b0, s4, 0, 0, 0);
    s4 = __builtin_amdgcn_mfma_f32_16x16x32_bf16(qf1, b1, s4, 0, 0, 0);
#pragma unroll
    for (int jj = 0; jj < 4; ++jj) {
      const int i = crow0 + jj;
      float s = (j <= i) ? s4[jj] : 0.f;
      rsum[jj] += s;
      P_s[i * 128 + (j ^ ((i & 7) << 3))] = rnbf(s);
    }
  }
  if (!(w & 1)) {  // even wave: zero-fill jt=w+1 so PV's boundary 32-block is defined
    const int j = (w + 1) * 16 + (l & 15);
#pragma unroll
    for (int jj = 0; jj < 4; ++jj) {
      const int i = crow0 + jj;
      P_s[i * 128 + (j ^ ((i & 7) << 3))] = 0;
    }
  }
  float di = 0.f;
#pragma unroll
  for (int jj = 0; jj < 8; ++jj) {
    di = fmaf(bf2f(qf0[jj]), z_s[(l >> 4) * 8 + jj], di);
    di = fmaf(bf2f(qf1[jj]), z_s[32 + (l >> 4) * 8 + jj], di);
  }
  di += __shfl_xor(di, 16);
  di += __shfl_xor(di, 32);
  if (l < 16) dinter_s[w * 16 + l] = di;
#pragma unroll
  for (int jj = 0; jj < 4; ++jj) {
    float r = rsum[jj];
    r += __shfl_xor(r, 1); r += __shfl_xor(r, 2);
    r += __shfl_xor(r, 4); r += __shfl_xor(r, 8);
    rsum[jj] = r;
  }
  // P_s / dinter_s rows are wave-local: wave-level LDS fence suffices.
  LGK0();

  f32x4 acc2[4] = {};
#pragma unroll
  for (int et = 0; et < 4; ++et) {
    const int e = et * 16 + (l & 15);
    const int sw = (e & 7) << 3, g = (l >> 4) * 8;
    bf16x8 s0 = *(const bf16x8*)&ST_s[e * 64 + (g ^ sw)];
    bf16x8 s1 = *(const bf16x8*)&ST_s[e * 64 + ((g + 32) ^ sw)];
    acc2[et] = __builtin_amdgcn_mfma_f32_16x16x32_bf16(qf0, s0, acc2[et], 0, 0, 0);
    acc2[et] = __builtin_amdgcn_mfma_f32_16x16x32_bf16(qf1, s1, acc2[et], 0, 0, 0);
  }
  const int prow = w * 16 + (l & 15);
  const int psw = (prow & 7) << 3;
  for (int jkt = 0; jkt <= (w >> 1); ++jkt) {
    bf16x8 pa = *(const bf16x8*)&P_s[prow * 128 + ((jkt * 32 + (l >> 4) * 8) ^ psw)];
#pragma unroll
    for (int et = 0; et < 4; ++et) {
      const int e = et * 16 + (l & 15);
      bf16x8 bv = *(const bf16x8*)&vT_s[e * 128 +
                                        ((jkt * 32 + (l >> 4) * 8) ^ ((e & 7) << 3))];
      acc2[et] = __builtin_amdgcn_mfma_f32_16x16x32_bf16(pa, bv, acc2[et], 0, 0, 0);
    }
  }
  float inv[4];
#pragma unroll
  for (int jj = 0; jj < 4; ++jj)
    inv[jj] = 1.0f / (rsum[jj] + dinter_s[crow0 + jj] + 1e-6f);
  const int b = bh >> 4, h = bh & 15;
#pragma unroll
  for (int et = 0; et < 4; ++et) {
    const int d = et * 16 + (l & 15);
#pragma unroll
    for (int jj = 0; jj < 4; ++jj) {
      const int t = c * CHUNK_ + crow0 + jj;
      yb[((size_t)(b * T_ + t) * H_ + h) * D_ + d] = rnbf(acc2[et][jj] * inv[jj]);
    }
  }
}

// ---------------------------------------------------------------------------
extern "C" void kernel_launch(void* const* d_in, const int* in_sizes, int n_in,
                              void* d_out, int out_size, void* d_ws, size_t ws_size,
                              hipStream_t stream) {
  const float* x = (const float*)d_in[0];
  const float* w_attn = (const float*)d_in[1];
  const float* w_proj = (const float*)d_in[2];
  float* out = (float*)d_out;

  ushort* xb = (ushort*)d_ws;                        // [8192,1024]
  ushort* wab = xb + (size_t)M_ * E_;                // [3072,1024]
  ushort* wpb = wab + (size_t)3 * E_ * E_;           // [1024,1024]
  ushort* qb = wpb + (size_t)E_ * E_;                // [bh][t][d]
  ushort* kbm = qb + (size_t)M_ * E_;                // [bh][t][d]
  ushort* kT = kbm + (size_t)M_ * E_;                // [bh][d][t]
  ushort* vT = kT + (size_t)M_ * E_;                 // [bh][d][t]
  ushort* yb = vT + (size_t)M_ * E_;                 // [B,T,H,D]
  ushort* STb = yb + (size_t)M_ * E_;                // [bh][c][e][d] bf16
  float* Schunk = (float*)(STb + (size_t)BH_ * NC_ * 4096);  // fp32
  float* zpart = Schunk + (size_t)BH_ * NC_ * 4096;  // [bh][c][2][64]
  float* zout = zpart + (size_t)BH_ * NC_ * 2 * 64;  // [bh][c][64]

  k_cvt3<<<12288, 256, 0, stream>>>(x, w_attn, w_proj, xb, wab, wpb);

  hipFuncSetAttribute((const void*)k_qkv2,
                      hipFuncAttributeMaxDynamicSharedMemorySize, 73728);
  hipFuncSetAttribute((const void*)k_proj2,
                      hipFuncAttributeMaxDynamicSharedMemorySize, 73728);

  k_qkv2<<<768, 512, 73728, stream>>>(xb, wab, qb, kbm, kT, vT, zpart);
  k_stats<<<1024, 256, 0, stream>>>(kT, vT, Schunk);
  k_prefix2<<<320, 256, 0, stream>>>(Schunk, STb, zpart, zout);
  k_out<<<1024, 512, 0, stream>>>(qb, kbm, vT, STb, zout, yb);
  k_proj2<<<256, 512, 73728, stream>>>(yb, wpb, out);
}

// Round 13
// 127.611 us; speedup vs baseline: 1.1621x; 1.0075x over previous
//
#include <hip/hip_runtime.h>
#include <math.h>

#define B_ 4
#define T_ 2048
#define E_ 1024
#define H_ 16
#define D_ 64
#define CHUNK_ 128
#define NC_ 16
#define BH_ (B_ * H_)   // 64
#define M_ (B_ * T_)    // 8192

typedef __attribute__((ext_vector_type(8))) short bf16x8;
typedef __attribute__((ext_vector_type(4))) float f32x4;

__device__ __forceinline__ ushort rnbf(float f) {
  unsigned u = __float_as_uint(f);
  unsigned r = (u + 0x7FFFu + ((u >> 16) & 1u)) >> 16;
  return (ushort)r;
}

__device__ __forceinline__ float bf2f(short s) {
  return __uint_as_float(((unsigned)(ushort)s) << 16);
}

__device__ __forceinline__ void gload_lds16(const void* g, void* l) {
  __builtin_amdgcn_global_load_lds(
      (const __attribute__((address_space(1))) unsigned int*)g,
      (__attribute__((address_space(3))) unsigned int*)l, 16, 0, 0);
}

#define VMW(N) do { asm volatile("s_waitcnt vmcnt(" #N ")" ::: "memory"); \
                    __builtin_amdgcn_sched_barrier(0); } while (0)
#define BARR() do { __builtin_amdgcn_s_barrier(); \
                    __builtin_amdgcn_sched_barrier(0); } while (0)
#define LGK0() do { asm volatile("s_waitcnt lgkmcnt(0)" ::: "memory"); \
                    __builtin_amdgcn_sched_barrier(0); } while (0)

// ---------------------------------------------------------------------------
// fused fp32 -> bf16 conversion for x, w_attn, w_proj (one launch)
// ---------------------------------------------------------------------------
#define N4X_ (M_ * E_ / 4)           // 2097152
#define N4A_ (3 * E_ * E_ / 4)       // 786432
#define N4P_ (E_ * E_ / 4)           // 262144
__global__ __launch_bounds__(256) void k_cvt3(
    const float* __restrict__ x, const float* __restrict__ wa,
    const float* __restrict__ wp, ushort* __restrict__ xb,
    ushort* __restrict__ wab, ushort* __restrict__ wpb) {
  int i = blockIdx.x * 256 + threadIdx.x;
  const float* src;
  ushort* dst;
  int off;
  if (i < N4X_) { src = x; dst = xb; off = i; }
  else if (i < N4X_ + N4A_) { src = wa; dst = wab; off = i - N4X_; }
  else { src = wp; dst = wpb; off = i - (N4X_ + N4A_); }
  float4 v = ((const float4*)src)[off];
  ushort4 o;
  o.x = rnbf(v.x); o.y = rnbf(v.y); o.z = rnbf(v.z); o.w = rnbf(v.w);
  ((ushort4*)dst)[off] = o;
}

// ---------------------------------------------------------------------------
// Pipelined MFMA GEMM core: C 128x256 tile = A[128xK] x B[256xK]^T, K=1024.
// 8 waves (2M x 4N). BK=32 slabs, 3-deep rotation (72 KB LDS, 2 blocks/CU).
// Per phase: VMW(3), barrier, 8 ds_read_b128 (chunk-XOR swizzled), stage
// slot t+2, 16 MFMA (setprio-wrapped). Proven 844 TF (R6/R11). R9/R10
// falsified the 256x256 deep pipeline at this shape. R7: launch_bounds
// min-waves stays <=4 — (512,6) caps VGPR ~85 and spills acc.
// ---------------------------------------------------------------------------
#define STG(sl_, tt_) { \
  gload_lds16(Asrc + (tt_) * 32, &lds[(sl_) * 4096 + tid * 8]); \
  gload_lds16(Bsrc0 + (tt_) * 32, &lds[12288 + (sl_) * 8192 + tid * 8]); \
  gload_lds16(Bsrc1 + (tt_) * 32, &lds[12288 + (sl_) * 8192 + 4096 + tid * 8]); }

#define LDFRAGS(sl_) \
  const ushort* pa = &lds[(sl_) * 4096 + aOff]; \
  a0 = *(const bf16x8*)pa;          a1 = *(const bf16x8*)(pa + 512); \
  a2 = *(const bf16x8*)(pa + 1024); a3 = *(const bf16x8*)(pa + 1536); \
  const ushort* pb = &lds[12288 + (sl_) * 8192 + bOff]; \
  b0 = *(const bf16x8*)pb;          b1 = *(const bf16x8*)(pb + 512); \
  b2 = *(const bf16x8*)(pb + 1024); b3 = *(const bf16x8*)(pb + 1536);

#define MM(i, j, A_, B_) \
  acc[i][j] = __builtin_amdgcn_mfma_f32_16x16x32_bf16(A_, B_, acc[i][j], 0, 0, 0)
#define MFMA16() do { __builtin_amdgcn_s_setprio(1); \
  MM(0,0,a0,b0); MM(0,1,a0,b1); MM(0,2,a0,b2); MM(0,3,a0,b3); \
  MM(1,0,a1,b0); MM(1,1,a1,b1); MM(1,2,a1,b2); MM(1,3,a1,b3); \
  MM(2,0,a2,b0); MM(2,1,a2,b1); MM(2,2,a2,b2); MM(2,3,a2,b3); \
  MM(3,0,a3,b0); MM(3,1,a3,b1); MM(3,2,a3,b2); MM(3,3,a3,b3); \
  __builtin_amdgcn_s_setprio(0); } while (0)

__device__ __forceinline__ void pipe_gemm(const ushort* __restrict__ Ag,
                                          const ushort* __restrict__ Bg,
                                          ushort* lds, f32x4 acc[4][4]) {
  const int tid = threadIdx.x;
  const int l = tid & 63, wv = tid >> 6;
  const int wm = wv >> 2, wn = wv & 3;
  const int c16 = l & 15, g4 = l >> 4;
  const int gch = (tid & 3) ^ ((tid >> 3) & 3);
  const ushort* Asrc = Ag + (size_t)(tid >> 2) * 1024 + gch * 8;
  const ushort* Bsrc0 = Bg + (size_t)(tid >> 2) * 1024 + gch * 8;
  const ushort* Bsrc1 = Bsrc0 + (size_t)128 * 1024;
  const int xq = (c16 >> 1) & 3;
  const int aOff = (wm * 64 + c16) * 32 + ((g4 ^ xq) << 3);
  const int bOff = (wn * 64 + c16) * 32 + ((g4 ^ xq) << 3);

  STG(0, 0);
  STG(1, 1);
  int sl = 0;
#pragma unroll 3
  for (int t = 0; t < 30; ++t) {
    const int slN = sl ? sl - 1 : 2;  // (sl+2)%3
    VMW(3); BARR();
    bf16x8 a0, a1, a2, a3, b0, b1, b2, b3;
    LDFRAGS(sl);
    STG(slN, t + 2);
    MFMA16();
    sl = (sl == 2) ? 0 : sl + 1;
  }
  {  // t=30, slab 0
    VMW(3); BARR();
    bf16x8 a0, a1, a2, a3, b0, b1, b2, b3;
    LDFRAGS(0);
    MFMA16();
  }
  {  // t=31, slab 1
    VMW(0); BARR();
    bf16x8 a0, a1, a2, a3, b0, b1, b2, b3;
    LDFRAGS(1);
    MFMA16();
  }
}

// ---------------------------------------------------------------------------
// Kernel 1: qkv = x @ w_attn^T; phi on q,k; q/k row-major, kT/vT transposed
// (per-wave LDS transpose), z chunk-partials fused.
// XCD-L2 mapping: xcd = b&7 owns bm slice [xcd*8, xcd*8+8), bm-fastest ->
// A slice (2 MB) L2-resident, B panel shared by co-running bm-blocks.
// ---------------------------------------------------------------------------
__global__ __launch_bounds__(512, 4) void k_qkv2(
    const ushort* __restrict__ xb, const ushort* __restrict__ wab,
    ushort* __restrict__ qg, ushort* __restrict__ kg,
    ushort* __restrict__ ktg, ushort* __restrict__ vtg,
    float* __restrict__ zp) {
  extern __shared__ ushort lds[];
  const int b = blockIdx.x;
  const int xcd = b & 7, idx = b >> 3;     // idx in [0,96)
  const int bm = xcd * 8 + (idx & 7);      // [0,64)
  const int bn = idx >> 3;                 // [0,12)
  const int tid = threadIdx.x;
  const int wv = tid >> 6, l = tid & 63;
  const int wm = wv >> 2, wn = wv & 3;
  const int c16 = l & 15, g4 = l >> 4;

  f32x4 acc[4][4] = {};
  pipe_gemm(xb + (size_t)bm * 128 * 1024, wab + (size_t)bn * 256 * 1024, lds, acc);

  // ---- epilogue ----
  BARR();  // pipeline LDS reads done; LDS reused as transpose buffers
  const int colbase = bn * 256 + wn * 64;
  const int which = colbase >> 10;
  const int h = (colbase & 1023) >> 6;
  const int rowbase = bm * 128 + wm * 64;
  const int bidx = rowbase >> 11;
  const int tbase = rowbase & 2047;
  const size_t bh = (size_t)(bidx * 16 + h);
  ushort* wlds = &lds[wv * 4096];  // per-wave 64d x 64t transpose tile
  float zpart[4] = {0.f, 0.f, 0.f, 0.f};
#pragma unroll
  for (int mf = 0; mf < 4; ++mf) {
#pragma unroll
    for (int nf = 0; nf < 4; ++nf) {
      float o[4];
#pragma unroll
      for (int j = 0; j < 4; ++j) {
        float u = acc[mf][nf][j];
        o[j] = (which < 2) ? ((u > 0.f) ? u + 1.f : expf(u)) : u;  // elu+1
      }
      const int d = nf * 16 + c16;
      if (which == 1) zpart[nf] += o[0] + o[1] + o[2] + o[3];
      if (which <= 1) {
        ushort* dst = (which == 0) ? qg : kg;
        const size_t rb = (bh * 2048 + tbase + mf * 16 + g4 * 4) * 64 + d;
#pragma unroll
        for (int j = 0; j < 4; ++j) dst[rb + (size_t)j * 64] = rnbf(o[j]);
      }
      if (which >= 1) {
        const int tb = (mf * 4 + g4) ^ ((d & 3) << 1);
        ushort4 pk;
        pk.x = rnbf(o[0]); pk.y = rnbf(o[1]); pk.z = rnbf(o[2]); pk.w = rnbf(o[3]);
        *(ushort4*)&wlds[d * 64 + tb * 4] = pk;
      }
    }
  }
  if (which == 1) {
    const int cc = tbase >> 7;
#pragma unroll
    for (int nf = 0; nf < 4; ++nf) {
      float zz = zpart[nf];
      zz += __shfl_xor(zz, 16);
      zz += __shfl_xor(zz, 32);
      if (l < 16) zp[((bh * NC_ + cc) * 2 + wm) * 64 + nf * 16 + l] = zz;
    }
  }
  if (which >= 1) {
    asm volatile("s_waitcnt lgkmcnt(0)" ::: "memory");
    __builtin_amdgcn_sched_barrier(0);
    ushort* tg = (which == 1) ? ktg : vtg;
#pragma unroll
    for (int it = 0; it < 8; ++it) {
      const int d = it * 8 + (l >> 3);
      const int t0 = (l & 7) * 8;
      const int blk = ((l & 7) * 2) ^ ((d & 3) << 1);
      bf16x8 vv_ = *(const bf16x8*)&wlds[d * 64 + blk * 4];
      *(bf16x8*)&tg[(bh * 64 + d) * 2048 + tbase + t0] = vv_;
    }
  }
}

// ---------------------------------------------------------------------------
// Kernel 5 (k_proj3, R13): out = y @ w_proj^T. 128x128 tile, 256 threads
// (4 waves, 2x2 of 64x64), BK=32, 3-slab 48 KB LDS -> 3 blocks/CU; grid
// 64x8 = 512 blocks <= 768 capacity -> single round with >=2 co-resident
// blocks/CU (restores m114 inter-block overlap that the old grid-256
// 1-block/CU config lacked). Same chunk-XOR swizzle / counted-vmcnt
// structure as pipe_gemm; 4 loads/stage -> VMW(4).
// ---------------------------------------------------------------------------
#define APB(sl_) ((sl_) * 4096)
#define BPB(sl_) (12288 + (sl_) * 4096)

#define STGP(sl_, tt_) { \
  gload_lds16(Asrc + (tt_) * 32,         &lds[APB(sl_) + tid * 8]); \
  gload_lds16(Asrc + (tt_) * 32 + 65536, &lds[APB(sl_) + 2048 + tid * 8]); \
  gload_lds16(Bsrc + (tt_) * 32,         &lds[BPB(sl_) + tid * 8]); \
  gload_lds16(Bsrc + (tt_) * 32 + 65536, &lds[BPB(sl_) + 2048 + tid * 8]); }

#define LDFRAGSP(sl_) \
  const ushort* pa = &lds[APB(sl_) + aOff]; \
  a0 = *(const bf16x8*)pa;          a1 = *(const bf16x8*)(pa + 512); \
  a2 = *(const bf16x8*)(pa + 1024); a3 = *(const bf16x8*)(pa + 1536); \
  const ushort* pb = &lds[BPB(sl_) + bOff]; \
  b0 = *(const bf16x8*)pb;          b1 = *(const bf16x8*)(pb + 512); \
  b2 = *(const bf16x8*)(pb + 1024); b3 = *(const bf16x8*)(pb + 1536);

__global__ __launch_bounds__(256, 2) void k_proj3(
    const ushort* __restrict__ yb, const ushort* __restrict__ wpb,
    float* __restrict__ out) {
  extern __shared__ ushort lds[];
  const int b = blockIdx.x;
  const int xcd = b & 7, idx = b >> 3;     // idx in [0,64)
  const int bm = xcd * 8 + (idx & 7);      // [0,64)
  const int bn = idx >> 3;                 // [0,8)
  const int tid = threadIdx.x;
  const int wv = tid >> 6, l = tid & 63;
  const int wm = wv >> 1, wn = wv & 1;
  const int c16 = l & 15, g4 = l >> 4;

  const ushort* Ag = yb + (size_t)bm * 128 * 1024;
  const ushort* Bg = wpb + (size_t)bn * 128 * 1024;
  const int gch = (tid & 3) ^ ((tid >> 3) & 3);
  const ushort* Asrc = Ag + (size_t)(tid >> 2) * 1024 + gch * 8;
  const ushort* Bsrc = Bg + (size_t)(tid >> 2) * 1024 + gch * 8;
  const int xq = (c16 >> 1) & 3;
  const int aOff = (wm * 64 + c16) * 32 + ((g4 ^ xq) << 3);
  const int bOff = (wn * 64 + c16) * 32 + ((g4 ^ xq) << 3);

  f32x4 acc[4][4] = {};

  STGP(0, 0);
  STGP(1, 1);
  int sl = 0;
#pragma unroll 3
  for (int t = 0; t < 30; ++t) {
    const int slN = sl ? sl - 1 : 2;  // (sl+2)%3
    VMW(4); BARR();
    bf16x8 a0, a1, a2, a3, b0, b1, b2, b3;
    LDFRAGSP(sl);
    STGP(slN, t + 2);
    MFMA16();
    sl = (sl == 2) ? 0 : sl + 1;
  }
  {  // t=30, slab 0
    VMW(4); BARR();
    bf16x8 a0, a1, a2, a3, b0, b1, b2, b3;
    LDFRAGSP(0);
    MFMA16();
  }
  {  // t=31, slab 1
    VMW(0); BARR();
    bf16x8 a0, a1, a2, a3, b0, b1, b2, b3;
    LDFRAGSP(1);
    MFMA16();
  }

  const int rowbase = bm * 128 + wm * 64 + g4 * 4;
  const int colbase = bn * 128 + wn * 64 + c16;
#pragma unroll
  for (int mf = 0; mf < 4; ++mf)
#pragma unroll
    for (int nf = 0; nf < 4; ++nf) {
      const size_t base = (size_t)(rowbase + mf * 16) * 1024 + colbase + nf * 16;
#pragma unroll
      for (int j = 0; j < 4; ++j)
        out[base + (size_t)j * 1024] = acc[mf][nf][j];
    }
}

// ---------------------------------------------------------------------------
// Kernel 2 (MFMA): per-chunk  ST[e][d] = sum_t v[t][e] k[t][d]  (fp32 out)
// ---------------------------------------------------------------------------
__global__ __launch_bounds__(256) void k_stats(const ushort* __restrict__ ktg,
                                               const ushort* __restrict__ vtg,
                                               float* __restrict__ Sc) {
  __shared__ __align__(16) ushort kT_s[64 * 128], vT_s[64 * 128];
  const int blk = blockIdx.x;
  const int bh = blk >> 4, c = blk & 15;
  const int tid = threadIdx.x;
  const int w = tid >> 6, l = tid & 63;
  const ushort* ktb = ktg + (size_t)bh * D_ * T_ + c * CHUNK_;
  const ushort* vtb = vtg + (size_t)bh * D_ * T_ + c * CHUNK_;
#pragma unroll
  for (int s2 = 0; s2 < 4; ++s2) {
    const int seg = w * 4 + s2;
    const int row = seg * 4 + (l >> 4);
    const int sb = ((l & 15) ^ (row & 7)) * 8;
    gload_lds16(ktb + (size_t)row * T_ + sb, &kT_s[seg * 512]);
    gload_lds16(vtb + (size_t)row * T_ + sb, &vT_s[seg * 512]);
  }
  __syncthreads();
  const int wr = w >> 1, wc = w & 1;
  f32x4 acc[2][2] = {};
#pragma unroll
  for (int kt = 0; kt < 4; ++kt) {
    const int g = kt * 32 + (l >> 4) * 8;
    bf16x8 av[2], bk[2];
#pragma unroll
    for (int rt = 0; rt < 2; ++rt) {
      const int e = wr * 32 + rt * 16 + (l & 15);
      av[rt] = *(const bf16x8*)&vT_s[e * 128 + (g ^ ((e & 7) << 3))];
    }
#pragma unroll
    for (int ct = 0; ct < 2; ++ct) {
      const int d = wc * 32 + ct * 16 + (l & 15);
      bk[ct] = *(const bf16x8*)&kT_s[d * 128 + (g ^ ((d & 7) << 3))];
    }
#pragma unroll
    for (int rt = 0; rt < 2; ++rt)
#pragma unroll
      for (int ct = 0; ct < 2; ++ct)
        acc[rt][ct] = __builtin_amdgcn_mfma_f32_16x16x32_bf16(av[rt], bk[ct],
                                                              acc[rt][ct], 0, 0, 0);
  }
  float* So = Sc + (size_t)blk * 4096;
#pragma unroll
  for (int rt = 0; rt < 2; ++rt)
#pragma unroll
    for (int ct = 0; ct < 2; ++ct)
#pragma unroll
      for (int jj = 0; jj < 4; ++jj)
        So[(wr * 32 + rt * 16 + (l >> 4) * 4 + jj) * 64 + wc * 32 + ct * 16 + (l & 15)] =
            acc[rt][ct][jj];
}

// ---------------------------------------------------------------------------
// Kernel 3: exclusive prefix over 16 chunks, parallelized.
// blocks 0..255: (bh, quarter) S-scan; blocks 256..319: z-scan per bh
// (z partials come in 2 halves per chunk from k_qkv2's wm split).
// ---------------------------------------------------------------------------
__global__ __launch_bounds__(256) void k_prefix2(const float* __restrict__ Sc,
                                                 ushort* __restrict__ STb,
                                                 const float* __restrict__ zp,
                                                 float* __restrict__ zout) {
  const int b = blockIdx.x;
  const int tid = threadIdx.x;
  if (b < 256) {
    const int bh = b >> 2, qt = b & 3;
    const float4* Sb = (const float4*)(Sc + (size_t)bh * NC_ * 4096) + qt * 256 + tid;
    ushort4* Ob = (ushort4*)(STb + (size_t)bh * NC_ * 4096) + qt * 256 + tid;
    float4 v[16];
#pragma unroll
    for (int c = 0; c < NC_; ++c) v[c] = Sb[c * 1024];
    float4 acc = make_float4(0.f, 0.f, 0.f, 0.f);
#pragma unroll
    for (int c = 0; c < NC_; ++c) {
      ushort4 o;
      o.x = rnbf(acc.x); o.y = rnbf(acc.y); o.z = rnbf(acc.z); o.w = rnbf(acc.w);
      Ob[c * 1024] = o;
      acc.x += v[c].x; acc.y += v[c].y; acc.z += v[c].z; acc.w += v[c].w;
    }
  } else {
    const int bh = b - 256;
    if (tid < 16) {
      const float4* zpb = (const float4*)(zp + (size_t)bh * NC_ * 128);
      float4* zob = (float4*)(zout + (size_t)bh * NC_ * 64);
      float4 t0[16], t1[16];
#pragma unroll
      for (int c = 0; c < NC_; ++c) {
        t0[c] = zpb[c * 32 + tid];
        t1[c] = zpb[c * 32 + 16 + tid];
      }
      float4 za = make_float4(0.f, 0.f, 0.f, 0.f);
#pragma unroll
      for (int c = 0; c < NC_; ++c) {
        zob[c * 16 + tid] = za;
        za.x += t0[c].x + t1[c].x; za.y += t0[c].y + t1[c].y;
        za.z += t0[c].z + t1[c].z; za.w += t0[c].w + t1[c].w;
      }
    }
  }
}

// ---------------------------------------------------------------------------
// Kernel 4 (MFMA): per-chunk output -> y bf16 [B,T,H,D].
// CAUSAL-AWARE (R12): wave w computes only key blocks jt <= w; even waves
// zero-fill the jt=w+1 strip; wave-local LDS fence instead of 2nd barrier.
// (R12 result: neutral — k_out is staging/latency-bound, kept as less work.)
// ---------------------------------------------------------------------------
__global__ __launch_bounds__(512, 4) void k_out(
    const ushort* __restrict__ qg, const ushort* __restrict__ kg,
    const ushort* __restrict__ vtg, const ushort* __restrict__ STb,
    const float* __restrict__ zg, ushort* __restrict__ yb) {
  __shared__ __align__(16) ushort k_s[128 * 64];
  __shared__ __align__(16) ushort vT_s[64 * 128];
  __shared__ __align__(16) ushort ST_s[64 * 64];
  __shared__ __align__(16) ushort P_s[128 * 128];
  __shared__ float z_s[64];
  __shared__ float dinter_s[128];
  const int blk = blockIdx.x;
  const int bh = blk >> 4, c = blk & 15;
  const int tid = threadIdx.x;
  const int w = tid >> 6, l = tid & 63;

  const ushort* kbase = kg + ((size_t)bh * T_ + c * CHUNK_) * D_;
  const ushort* vbase = vtg + (size_t)bh * D_ * T_ + c * CHUNK_;
  const ushort* sbase = STb + ((size_t)bh * NC_ + c) * 4096;
  {
    int seg = w, row = seg * 8 + (l >> 3);
    gload_lds16(kbase + (size_t)row * 64 + ((l & 7) ^ (row & 7)) * 8, &k_s[seg * 512]);
    seg = w + 8; row = seg * 8 + (l >> 3);
    gload_lds16(kbase + (size_t)row * 64 + ((l & 7) ^ (row & 7)) * 8, &k_s[seg * 512]);
  }
  {
    int seg = w, row = seg * 4 + (l >> 4);
    gload_lds16(vbase + (size_t)row * T_ + ((l & 15) ^ (row & 7)) * 8, &vT_s[seg * 512]);
    seg = w + 8; row = seg * 4 + (l >> 4);
    gload_lds16(vbase + (size_t)row * T_ + ((l & 15) ^ (row & 7)) * 8, &vT_s[seg * 512]);
  }
  {
    const int seg = w, row = seg * 8 + (l >> 3);
    gload_lds16(sbase + (size_t)row * 64 + ((l & 7) ^ (row & 7)) * 8, &ST_s[seg * 512]);
  }
  if (tid < 64) z_s[tid] = zg[((size_t)bh * NC_ + c) * 64 + tid];
  const int arow = w * 16 + (l & 15);
  const ushort* qrow = qg + ((size_t)bh * T_ + c * CHUNK_ + arow) * D_ + (l >> 4) * 8;
  bf16x8 qf0 = *(const bf16x8*)(qrow);
  bf16x8 qf1 = *(const bf16x8*)(qrow + 32);
  __syncthreads();

  // ---- causal QK^T: wave w only needs key blocks jt <= w ----
  const int crow0 = w * 16 + (l >> 4) * 4;
  float rsum[4] = {0.f, 0.f, 0.f, 0.f};
  for (int jt = 0; jt <= w; ++jt) {
    const int j = jt * 16 + (l & 15);
    const int sw = (j & 7) << 3, g = (l >> 4) * 8;
    bf16x8 b0 = *(const bf16x8*)&k_s[j * 64 + (g ^ sw)];
    bf16x8 b1 = *(const bf16x8*)&k_s[j * 64 + ((g + 32) ^ sw)];
    f32x4 s4 = {0.f, 0.f, 0.f, 0.f};
    s4 = __builtin_amdgcn_mfma_f32_16x16x32_bf16(qf0, b0, s4, 0, 0, 0);
    s4 = __builtin_amdgcn_mfma_f32_16x16x32_bf16(qf1, b1, s4, 0, 0, 0);
#pragma unroll
    for (int jj = 0; jj < 4; ++jj) {
      const int i = crow0 + jj;
      float s = (j <= i) ? s4[jj] : 0.f;
      rsum[jj] += s;
      P_s[i * 128 + (j ^ ((i & 7) << 3))] = rnbf(s);
    }
  }
  if (!(w & 1)) {  // even wave: zero-fill jt=w+1 so PV's boundary 32-block is defined
    const int j = (w + 1) * 16 + (l & 15);
#pragma unroll
    for (int jj = 0; jj < 4; ++jj) {
      const int i = crow0 + jj;
      P_s[i * 128 + (j ^ ((i & 7) << 3))] = 0;
    }
  }
  float di = 0.f;
#pragma unroll
  for (int jj = 0; jj < 8; ++jj) {
    di = fmaf(bf2f(qf0[jj]), z_s[(l >> 4) * 8 + jj], di);
    di = fmaf(bf2f(qf1[jj]), z_s[32 + (l >> 4) * 8 + jj], di);
  }
  di += __shfl_xor(di, 16);
  di += __shfl_xor(di, 32);
  if (l < 16) dinter_s[w * 16 + l] = di;
#pragma unroll
  for (int jj = 0; jj < 4; ++jj) {
    float r = rsum[jj];
    r += __shfl_xor(r, 1); r += __shfl_xor(r, 2);
    r += __shfl_xor(r, 4); r += __shfl_xor(r, 8);
    rsum[jj] = r;
  }
  // P_s / dinter_s rows are wave-local: wave-level LDS fence suffices.
  LGK0();

  f32x4 acc2[4] = {};
#pragma unroll
  for (int et = 0; et < 4; ++et) {
    const int e = et * 16 + (l & 15);
    const int sw = (e & 7) << 3, g = (l >> 4) * 8;
    bf16x8 s0 = *(const bf16x8*)&ST_s[e * 64 + (g ^ sw)];
    bf16x8 s1 = *(const bf16x8*)&ST_s[e * 64 + ((g + 32) ^ sw)];
    acc2[et] = __builtin_amdgcn_mfma_f32_16x16x32_bf16(qf0, s0, acc2[et], 0, 0, 0);
    acc2[et] = __builtin_amdgcn_mfma_f32_16x16x32_bf16(qf1, s1, acc2[et], 0, 0, 0);
  }
  const int prow = w * 16 + (l & 15);
  const int psw = (prow & 7) << 3;
  for (int jkt = 0; jkt <= (w >> 1); ++jkt) {
    bf16x8 pa = *(const bf16x8*)&P_s[prow * 128 + ((jkt * 32 + (l >> 4) * 8) ^ psw)];
#pragma unroll
    for (int et = 0; et < 4; ++et) {
      const int e = et * 16 + (l & 15);
      bf16x8 bv = *(const bf16x8*)&vT_s[e * 128 +
                                        ((jkt * 32 + (l >> 4) * 8) ^ ((e & 7) << 3))];
      acc2[et] = __builtin_amdgcn_mfma_f32_16x16x32_bf16(pa, bv, acc2[et], 0, 0, 0);
    }
  }
  float inv[4];
#pragma unroll
  for (int jj = 0; jj < 4; ++jj)
    inv[jj] = 1.0f / (rsum[jj] + dinter_s[crow0 + jj] + 1e-6f);
  const int b = bh >> 4, h = bh & 15;
#pragma unroll
  for (int et = 0; et < 4; ++et) {
    const int d = et * 16 + (l & 15);
#pragma unroll
    for (int jj = 0; jj < 4; ++jj) {
      const int t = c * CHUNK_ + crow0 + jj;
      yb[((size_t)(b * T_ + t) * H_ + h) * D_ + d] = rnbf(acc2[et][jj] * inv[jj]);
    }
  }
}

// ---------------------------------------------------------------------------
extern "C" void kernel_launch(void* const* d_in, const int* in_sizes, int n_in,
                              void* d_out, int out_size, void* d_ws, size_t ws_size,
                              hipStream_t stream) {
  const float* x = (const float*)d_in[0];
  const float* w_attn = (const float*)d_in[1];
  const float* w_proj = (const float*)d_in[2];
  float* out = (float*)d_out;

  ushort* xb = (ushort*)d_ws;                        // [8192,1024]
  ushort* wab = xb + (size_t)M_ * E_;                // [3072,1024]
  ushort* wpb = wab + (size_t)3 * E_ * E_;           // [1024,1024]
  ushort* qb = wpb + (size_t)E_ * E_;                // [bh][t][d]
  ushort* kbm = qb + (size_t)M_ * E_;                // [bh][t][d]
  ushort* kT = kbm + (size_t)M_ * E_;                // [bh][d][t]
  ushort* vT = kT + (size_t)M_ * E_;                 // [bh][d][t]
  ushort* yb = vT + (size_t)M_ * E_;                 // [B,T,H,D]
  ushort* STb = yb + (size_t)M_ * E_;                // [bh][c][e][d] bf16
  float* Schunk = (float*)(STb + (size_t)BH_ * NC_ * 4096);  // fp32
  float* zpart = Schunk + (size_t)BH_ * NC_ * 4096;  // [bh][c][2][64]
  float* zout = zpart + (size_t)BH_ * NC_ * 2 * 64;  // [bh][c][64]

  k_cvt3<<<12288, 256, 0, stream>>>(x, w_attn, w_proj, xb, wab, wpb);

  hipFuncSetAttribute((const void*)k_qkv2,
                      hipFuncAttributeMaxDynamicSharedMemorySize, 73728);
  hipFuncSetAttribute((const void*)k_proj3,
                      hipFuncAttributeMaxDynamicSharedMemorySize, 49152);

  k_qkv2<<<768, 512, 73728, stream>>>(xb, wab, qb, kbm, kT, vT, zpart);
  k_stats<<<1024, 256, 0, stream>>>(kT, vT, Schunk);
  k_prefix2<<<320, 256, 0, stream>>>(Schunk, STb, zpart, zout);
  k_out<<<1024, 512, 0, stream>>>(qb, kbm, vT, STb, zout, yb);
  k_proj3<<<512, 256, 49152, stream>>>(yb, wpb, out);
}